// Round 3
// baseline (2500.997 us; speedup 1.0000x reference)
//
#include <hip/hip_runtime.h>
#include <hip/hip_bf16.h>
#include <math.h>

#define B_    64
#define L_    512
#define C_    321
#define PRED_ 96
#define N_    64
#define HID_  32
#define BC_   (B_*C_)   // 20544
#define SROW_ 528       // padded stride for seasonal rows (520 used)
#define EPS_  1e-5f
#define ALPHA_ 0.2f
#define GR_   16        // rows per block in bn-stat kernels
#define RB_   8         // rows per block in k5a
#define NBLK2_ (BC_/GR_) // 1284

typedef __attribute__((ext_vector_type(8))) short bf16x8;
typedef __attribute__((ext_vector_type(4))) float f32x4;

__device__ __forceinline__ float gelu_f(float x){
  return 0.5f*x*(1.0f + erff(x*0.70710678118654752440f));
}
__device__ __forceinline__ unsigned short bf16bits(float x){
  __hip_bfloat16 h = __float2bfloat16(x);
  return *(unsigned short*)&h;
}

// ---------- K0: fold seas/tr matmuls through fus; store bf16 col-major [j][k] ----------
__global__ __launch_bounds__(256) void k0_fold(
    const float* __restrict__ seas_w, const float* __restrict__ tr_w,
    const float* __restrict__ fus_w,
    __hip_bfloat16* __restrict__ Wsf, __hip_bfloat16* __restrict__ Wtf) {
  int idx = blockIdx.x*256 + threadIdx.x;
  if (idx >= 96*1536) return;
  int j = idx / 1536, k = idx - j*1536;
  float acc = 0.f;
  if (k < 1024) {
    for (int i=0;i<96;++i) acc = fmaf(fus_w[j*192+i], seas_w[i*1024+k], acc);
    Wsf[(size_t)j*1024 + k] = __float2bfloat16(acc);
  } else {
    int l = k - 1024;
    for (int i=0;i<96;++i) acc = fmaf(fus_w[j*192+96+i], tr_w[i*512+l], acc);
    Wtf[(size_t)j*512 + l] = __float2bfloat16(acc);
  }
}

// ---------- K0b: combined bias + column-sum of folded trend matrix ----------
__global__ void k0b_bias(
    const float* __restrict__ seas_b, const float* __restrict__ tr_b,
    const float* __restrict__ fus_w, const float* __restrict__ fus_b,
    const float* __restrict__ tr_w,
    float* __restrict__ biasc, float* __restrict__ colsumT) {
  __shared__ float rowsum[96];
  int t = threadIdx.x;
  if (t < 96) {
    float s = 0.f;
    for (int l=0;l<512;++l) s += tr_w[t*512+l];
    rowsum[t] = s;
  }
  __syncthreads();
  if (t < 96) {
    float acc = fus_b[t], cs = 0.f;
    for (int i=0;i<96;++i) {
      acc = fmaf(fus_w[t*192+i],    seas_b[i], acc);
      acc = fmaf(fus_w[t*192+96+i], tr_b[i],   acc);
      cs  = fmaf(fus_w[t*192+96+i], rowsum[i], cs);
    }
    biasc[t] = acc; colsumT[t] = cs;
  }
}

// ---------- K1: RevIN stats + chunked EMA scan (4 threads/row) ----------
__global__ __launch_bounds__(256) void k1_revin_ema(
    const float* __restrict__ x, const float* __restrict__ rev_w, const float* __restrict__ rev_b,
    float* __restrict__ s_raw, __hip_bfloat16* __restrict__ t_bf, float* __restrict__ rowpar) {
  __shared__ float lf[4][64];
  __shared__ float psum[4][64], psq[4][64];
  int tid = threadIdx.x;
  int q = tid >> 6, r = tid & 63;
  int row = blockIdx.x*64 + r;
  int b = row / C_, c = row - b*C_;
  const float* xp = x + (size_t)b*L_*C_ + c;
  int l0 = q*128;
  float tloc = 0.f, sum = 0.f, sq = 0.f;
  for (int i=0;i<128;++i) {
    float v = xp[(size_t)(l0+i)*C_];
    sum += v; sq = fmaf(v,v,sq);
    if (q==0 && i==0) tloc = v;
    else tloc = fmaf(ALPHA_, v, 0.8f*tloc);
  }
  lf[q][r] = tloc; psum[q][r] = sum; psq[q][r] = sq;
  __syncthreads();
  float cin = (q==0) ? 0.f : lf[q-1][r];
  if (q==0) {
    float S=0.f, Q=0.f;
    for (int qq=0;qq<4;++qq){ S += psum[qq][r]; Q += psq[qq][r]; }
    float mean = S*(1.0f/512.0f);
    float var  = (Q - S*S*(1.0f/512.0f))*(1.0f/511.0f);
    var = fmaxf(var, 0.f);
    float stdv = sqrtf(var) + EPS_;
    float rwc = rev_w[c], rbc = rev_b[c];
    float a = rwc / stdv;
    float g = rbc - mean*a;
    float inva = stdv / rwc;
    ((float4*)rowpar)[row] = make_float4(a, g, mean, inva);
  }
  float loc = 0.f, f = 1.f, vlast = 0.f, tlast = 0.f;
  for (int i=0;i<128;++i) {
    float v = xp[(size_t)(l0+i)*C_];
    if (q==0 && i==0) loc = v;
    else loc = fmaf(ALPHA_, v, 0.8f*loc);
    f *= 0.8f;
    float tt = fmaf(f, cin, loc);
    s_raw[(size_t)row*SROW_ + l0 + i] = v - tt;
    t_bf[(size_t)row*512 + l0 + i] = __float2bfloat16(tt);
    vlast = v; tlast = tt;
  }
  if (q==3) {
    float slast = vlast - tlast;
    for (int k=0;k<8;++k) s_raw[(size_t)row*SROW_ + 512 + k] = slast;
  }
}

// ---------- K2: BN1 statistics of gelu(fc1(sp)) ----------
__global__ __launch_bounds__(256) void k2_bn1stats(
    const float* __restrict__ s_raw, const float* __restrict__ rowpar,
    const float* __restrict__ fc1_w, const float* __restrict__ fc1_b,
    float* __restrict__ partials) {
  __shared__ float sl[GR_*SROW_];
  __shared__ float w1[512];
  __shared__ float b1[32];
  __shared__ float al[GR_];
  __shared__ float red[2][GR_*64];
  int t = threadIdx.x;
  int row0 = blockIdx.x*GR_;
  if (t < GR_) al[t] = rowpar[(size_t)(row0+t)*4];
  for (int idx=t; idx<512; idx+=256) w1[idx] = fc1_w[idx];
  if (t < 32) b1[t] = fc1_b[t];
  __syncthreads();
  for (int idx=t; idx<GR_*520; idx+=256) {
    int rr = idx/520, cc = idx - rr*520;
    sl[rr*SROW_+cc] = s_raw[(size_t)(row0+rr)*SROW_+cc] * al[rr];
  }
  __syncthreads();
  int lr = t >> 4, ng = t & 15;
  for (int q=0;q<4;++q) {
    int n = ng + 16*q;
    float sp[16];
    #pragma unroll
    for (int p=0;p<16;++p) sp[p] = sl[lr*SROW_ + n*8 + p];
    float s1=0.f, s2=0.f;
    #pragma unroll
    for (int hid=0; hid<32; ++hid) {
      float acc = b1[hid];
      #pragma unroll
      for (int p=0;p<16;++p) acc = fmaf(sp[p], w1[hid*16+p], acc);
      float gv = gelu_f(acc);
      s1 += gv; s2 = fmaf(gv,gv,s2);
    }
    red[0][lr*64+n] = s1;
    red[1][lr*64+n] = s2;
  }
  __syncthreads();
  if (t < 64) {
    float S1=0.f, S2=0.f;
    for (int lr2=0; lr2<GR_; ++lr2) { S1 += red[0][lr2*64+t]; S2 += red[1][lr2*64+t]; }
    partials[((size_t)blockIdx.x*64+t)*2+0] = S1;
    partials[((size_t)blockIdx.x*64+t)*2+1] = S2;
  }
}

// ---------- bn reduce ----------
__global__ __launch_bounds__(256) void k_bnreduce(
    const float* __restrict__ partials, int nblk,
    const float* __restrict__ bnw, const float* __restrict__ bnb,
    float* __restrict__ scale, float* __restrict__ shift) {
  __shared__ float red[2][256];
  int n = blockIdx.x, t = threadIdx.x;
  float s1=0.f, s2=0.f;
  for (int i=t; i<nblk; i+=256) {
    s1 += partials[((size_t)i*64+n)*2+0];
    s2 += partials[((size_t)i*64+n)*2+1];
  }
  red[0][t]=s1; red[1][t]=s2;
  __syncthreads();
  for (int off=128; off>0; off>>=1) {
    if (t<off) { red[0][t]+=red[0][t+off]; red[1][t]+=red[1][t+off]; }
    __syncthreads();
  }
  if (t==0) {
    const float count = (float)BC_ * 32.0f;
    float mu = red[0][0]/count;
    float var = red[1][0]/count - mu*mu;
    float sc = rsqrtf(var + EPS_) * bnw[n];
    scale[n] = sc;
    shift[n] = bnb[n] - mu*sc;
  }
}

// ---------- K3: BN2 statistics (rolling 3-tap window, no h[32]) ----------
__global__ __launch_bounds__(256, 4) void k3_bn2stats(
    const float* __restrict__ s_raw, const float* __restrict__ rowpar,
    const float* __restrict__ fc1_w, const float* __restrict__ fc1_b,
    const float* __restrict__ scale1, const float* __restrict__ shift1,
    const float* __restrict__ conv_w, const float* __restrict__ conv_b,
    float* __restrict__ partials) {
  __shared__ float sl[GR_*SROW_];
  __shared__ float w1[512];
  __shared__ float b1[32];
  __shared__ float al[GR_];
  __shared__ float sc1[64], sh1[64], cw[192], cb[64];
  __shared__ float red[2][GR_*64];
  int t = threadIdx.x;
  int row0 = blockIdx.x*GR_;
  if (t < GR_) al[t] = rowpar[(size_t)(row0+t)*4];
  for (int idx=t; idx<512; idx+=256) w1[idx] = fc1_w[idx];
  if (t < 32) b1[t] = fc1_b[t];
  if (t < 64) { sc1[t]=scale1[t]; sh1[t]=shift1[t]; cb[t]=conv_b[t]; }
  if (t >= 64 && t < 256) cw[t-64] = conv_w[t-64];
  __syncthreads();
  for (int idx=t; idx<GR_*520; idx+=256) {
    int rr = idx/520, cc = idx - rr*520;
    sl[rr*SROW_+cc] = s_raw[(size_t)(row0+rr)*SROW_+cc] * al[rr];
  }
  __syncthreads();
  int lr = t >> 4, ng = t & 15;
  for (int q=0;q<4;++q) {
    int n = ng + 16*q;
    float sp[16];
    #pragma unroll
    for (int p=0;p<16;++p) sp[p] = sl[lr*SROW_ + n*8 + p];
    float scn = sc1[n], shn = sh1[n];
    auto hfun = [&](int k)->float {
      float acc = b1[k];
      #pragma unroll
      for (int p=0;p<16;++p) acc = fmaf(sp[p], w1[k*16+p], acc);
      return fmaf(gelu_f(acc), scn, shn);
    };
    float w0=cw[n*3], wm=cw[n*3+1], wpp=cw[n*3+2], cbn=cb[n];
    float s1=0.f, s2=0.f;
    float hm=0.f, hc=hfun(0), hp=hfun(1);
    #pragma unroll
    for (int k2=0;k2<32;++k2) {
      float cv = cbn;
      if (k2>0)  cv = fmaf(hm, w0, cv);
      cv = fmaf(hc, wm, cv);
      if (k2<31) cv = fmaf(hp, wpp, cv);
      float gv = gelu_f(cv);
      s1 += gv; s2 = fmaf(gv,gv,s2);
      hm = hc; hc = hp;
      hp = (k2+2<32) ? hfun(k2+2) : 0.f;
    }
    red[0][lr*64+n]=s1; red[1][lr*64+n]=s2;
  }
  __syncthreads();
  if (t < 64) {
    float S1=0.f, S2=0.f;
    for (int lr2=0; lr2<GR_; ++lr2) { S1 += red[0][lr2*64+t]; S2 += red[1][lr2*64+t]; }
    partials[((size_t)blockIdx.x*64+t)*2+0] = S1;
    partials[((size_t)blockIdx.x*64+t)*2+1] = S2;
  }
}

// ---------- K5a: per-row pipeline -> LayerNorm'd y (bf16), rolling window ----------
__global__ __launch_bounds__(256, 4) void k5a_pipeline(
    const float* __restrict__ s_raw, const float* __restrict__ rowpar,
    const float* __restrict__ fc1_w, const float* __restrict__ fc1_b,
    const float* __restrict__ scale1, const float* __restrict__ shift1,
    const float* __restrict__ conv_w, const float* __restrict__ conv_b,
    const float* __restrict__ scale2, const float* __restrict__ shift2,
    const float* __restrict__ fc2_w, const float* __restrict__ fc2_b,
    const float* __restrict__ m1_w, const float* __restrict__ m1_b,
    const float* __restrict__ m2_w, const float* __restrict__ m2_b,
    const float* __restrict__ gl_scale,
    const float* __restrict__ ln_w, const float* __restrict__ ln_b,
    __hip_bfloat16* __restrict__ ybf) {
  __shared__ float sl[RB_*SROW_];
  __shared__ float pl[RB_*64];
  __shared__ float hl[RB_*128];
  __shared__ float wl[RB_*64];
  __shared__ float rp[RB_];
  __shared__ float w1[512], b1[32], cw[192], cb[64];
  __shared__ float sc1[64], sh1[64], sc2[64], sh2[64];
  __shared__ float w2s[512], b2s[16], lnw[16], lnb[16];
  int t = threadIdx.x;
  int row0 = blockIdx.x*RB_;
  if (t < RB_) rp[t] = rowpar[(size_t)(row0+t)*4];
  for (int idx=t; idx<512; idx+=256) { w1[idx]=fc1_w[idx]; w2s[idx]=fc2_w[idx]; }
  if (t<32) b1[t]=fc1_b[t];
  if (t<16) { b2s[t]=fc2_b[t]; lnw[t]=ln_w[t]; lnb[t]=ln_b[t]; }
  if (t<64) { sc1[t]=scale1[t]; sh1[t]=shift1[t]; sc2[t]=scale2[t]; sh2[t]=shift2[t]; cb[t]=conv_b[t]; }
  if (t>=64 && t<256) cw[t-64]=conv_w[t-64];
  __syncthreads();
  for (int idx=t; idx<RB_*520; idx+=256) {
    int rr = idx/520, cc = idx - rr*520;
    sl[rr*SROW_+cc] = s_raw[(size_t)(row0+rr)*SROW_+cc] * rp[rr];
  }
  __syncthreads();
  float glv = gl_scale[0];
  // P1: pooled
  for (int idx=t; idx<RB_*64; idx+=256) {
    int rr = idx>>6, n = idx&63;
    float s=0.f;
    #pragma unroll
    for (int p=0;p<16;++p) s += sl[rr*SROW_ + n*8 + p];
    pl[idx] = s*(1.0f/16.0f);
  }
  __syncthreads();
  // P2: hidden = gelu(m1 @ pooled + b)
  for (int idx=t; idx<RB_*128; idx+=256) {
    int rr = idx>>7, i = idx&127;
    float acc = m1_b[i];
    for (int k2=0;k2<64;++k2) acc = fmaf(pl[rr*64+k2], m1_w[i*64+k2], acc);
    hl[idx] = gelu_f(acc);
  }
  __syncthreads();
  // P3: w = sigmoid(m2 @ hidden + b)
  for (int idx=t; idx<RB_*64; idx+=256) {
    int rr = idx>>6, n = idx&63;
    float acc = m2_b[n];
    for (int k2=0;k2<128;++k2) acc = fmaf(hl[rr*128+k2], m2_w[n*128+k2], acc);
    wl[idx] = 1.0f/(1.0f + expf(-acc));
  }
  __syncthreads();
  // P4: per-(row,n) rolling-window pipeline -> LN'd y -> packed bf16 stores
  for (int idx=t; idx<RB_*64; idx+=256) {
    int rr = idx>>6, n = idx&63;
    float sp[16];
    #pragma unroll
    for (int p=0;p<16;++p) sp[p] = sl[rr*SROW_ + n*8 + p];
    float scn=sc1[n], shn=sh1[n];
    auto hfun = [&](int k)->float {
      float acc=b1[k];
      #pragma unroll
      for (int p=0;p<16;++p) acc=fmaf(sp[p], w1[k*16+p], acc);
      return fmaf(gelu_f(acc), scn, shn);
    };
    float w0=cw[n*3], wm=cw[n*3+1], wpp=cw[n*3+2], cbn=cb[n];
    float sc2n=sc2[n], sh2n=sh2[n];
    float yv[16];
    #pragma unroll
    for (int p=0;p<16;++p) yv[p]=b2s[p];
    float hm=0.f, hc=hfun(0), hp=hfun(1);
    #pragma unroll
    for (int k2=0;k2<32;++k2) {
      float cv=cbn;
      if (k2>0)  cv=fmaf(hm, w0, cv);
      cv=fmaf(hc, wm, cv);
      if (k2<31) cv=fmaf(hp, wpp, cv);
      float h2v=fmaf(gelu_f(cv), sc2n, sh2n);
      #pragma unroll
      for (int p=0;p<16;++p) yv[p]=fmaf(h2v, w2s[p*32+k2], yv[p]);
      hm = hc; hc = hp;
      hp = (k2+2<32) ? hfun(k2+2) : 0.f;
    }
    float smul = 3.0f + glv*wl[idx];
    float mu=0.f;
    #pragma unroll
    for (int p=0;p<16;++p) { yv[p]=fmaf(sp[p], smul, yv[p]); mu+=yv[p]; }
    mu *= (1.0f/16.0f);
    float var=0.f;
    #pragma unroll
    for (int p=0;p<16;++p){ float d=yv[p]-mu; var=fmaf(d,d,var); }
    var *= (1.0f/16.0f);
    float rs = rsqrtf(var + EPS_);
    unsigned int wds[8];
    #pragma unroll
    for (int j=0;j<8;++j) {
      unsigned int lo = bf16bits(fmaf((yv[2*j]-mu)*rs,   lnw[2*j],   lnb[2*j]));
      unsigned int hi = bf16bits(fmaf((yv[2*j+1]-mu)*rs, lnw[2*j+1], lnb[2*j+1]));
      wds[j] = lo | (hi<<16);
    }
    size_t ybase = (size_t)(row0+rr)*1024 + n*16;
    uint4* dst = (uint4*)&ybf[ybase];
    dst[0] = make_uint4(wds[0],wds[1],wds[2],wds[3]);
    dst[1] = make_uint4(wds[4],wds[5],wds[6],wds[7]);
  }
}

// ---------- K5b: bf16 MFMA GEMM  out = y@Wsf^T + a*(t@Wtf^T) + g*colsum + biasc ----------
__global__ __launch_bounds__(256) void k5b_gemm(
    const __hip_bfloat16* __restrict__ ybf, const __hip_bfloat16* __restrict__ tbf,
    const __hip_bfloat16* __restrict__ Wsf, const __hip_bfloat16* __restrict__ Wtf,
    const float* __restrict__ rowpar, const float* __restrict__ rev_b,
    const float* __restrict__ biasc, const float* __restrict__ colsumT,
    float* __restrict__ out) {
  __shared__ __align__(16) __hip_bfloat16 As[64*72];
  __shared__ __align__(16) __hip_bfloat16 Bs[96*72];
  __shared__ float rp[256];
  __shared__ float rbl[64];
  __shared__ int   obase[64];
  __shared__ float bcl[96], csl[96];
  int tid = threadIdx.x;
  int row0 = blockIdx.x*64;
  rp[tid] = rowpar[(size_t)row0*4 + tid];
  if (tid < 64) {
    int row = row0 + tid; int b = row/C_; int c = row - b*C_;
    rbl[tid] = rev_b[c]; obase[tid] = b*PRED_*C_ + c;
  }
  if (tid >= 128 && tid < 224) { bcl[tid-128]=biasc[tid-128]; csl[tid-128]=colsumT[tid-128]; }
  int lane = tid & 63, w = tid >> 6;
  int fr = lane & 15, fg = lane >> 4;
  f32x4 acc[6];
  #pragma unroll
  for (int n=0;n<6;++n) acc[n] = (f32x4){0.f,0.f,0.f,0.f};
  // ---- trend phase: K=512 ----
  for (int ks=0; ks<8; ++ks) {
    __syncthreads();
    #pragma unroll
    for (int u=0;u<2;++u) {
      int i = tid + u*256; int rr = i>>3, ch = i&7;
      *(uint4*)&As[rr*72 + ch*8] = *(const uint4*)&tbf[(size_t)(row0+rr)*512 + ks*64 + ch*8];
    }
    #pragma unroll
    for (int u=0;u<3;++u) {
      int i = tid + u*256; int rr = i>>3, ch = i&7;
      *(uint4*)&Bs[rr*72 + ch*8] = *(const uint4*)&Wtf[(size_t)rr*512 + ks*64 + ch*8];
    }
    __syncthreads();
    #pragma unroll
    for (int ksub=0; ksub<2; ++ksub) {
      bf16x8 av = *(bf16x8*)&As[(w*16+fr)*72 + ksub*32 + fg*8];
      #pragma unroll
      for (int n=0;n<6;++n) {
        bf16x8 bv = *(bf16x8*)&Bs[(n*16+fr)*72 + ksub*32 + fg*8];
        acc[n] = __builtin_amdgcn_mfma_f32_16x16x32_bf16(av, bv, acc[n], 0,0,0);
      }
    }
  }
  #pragma unroll
  for (int n=0;n<6;++n) {
    #pragma unroll
    for (int reg=0;reg<4;++reg) {
      int rloc = w*16 + fg*4 + reg;
      acc[n][reg] *= rp[rloc*4+0];
    }
  }
  // ---- seasonal phase: K=1024 ----
  for (int ks=0; ks<16; ++ks) {
    __syncthreads();
    #pragma unroll
    for (int u=0;u<2;++u) {
      int i = tid + u*256; int rr = i>>3, ch = i&7;
      *(uint4*)&As[rr*72 + ch*8] = *(const uint4*)&ybf[(size_t)(row0+rr)*1024 + ks*64 + ch*8];
    }
    #pragma unroll
    for (int u=0;u<3;++u) {
      int i = tid + u*256; int rr = i>>3, ch = i&7;
      *(uint4*)&Bs[rr*72 + ch*8] = *(const uint4*)&Wsf[(size_t)rr*1024 + ks*64 + ch*8];
    }
    __syncthreads();
    #pragma unroll
    for (int ksub=0; ksub<2; ++ksub) {
      bf16x8 av = *(bf16x8*)&As[(w*16+fr)*72 + ksub*32 + fg*8];
      #pragma unroll
      for (int n=0;n<6;++n) {
        bf16x8 bv = *(bf16x8*)&Bs[(n*16+fr)*72 + ksub*32 + fg*8];
        acc[n] = __builtin_amdgcn_mfma_f32_16x16x32_bf16(av, bv, acc[n], 0,0,0);
      }
    }
  }
  #pragma unroll
  for (int n=0;n<6;++n) {
    int col = n*16 + fr;
    float cs = csl[col], bc = bcl[col];
    #pragma unroll
    for (int reg=0;reg<4;++reg) {
      int rloc = w*16 + fg*4 + reg;
      float g = rp[rloc*4+1], meanv = rp[rloc*4+2], inva = rp[rloc*4+3];
      float val = acc[n][reg] + g*cs + bc;
      val = (val - rbl[rloc])*inva + meanv;
      out[(size_t)obase[rloc] + (size_t)col*C_] = val;
    }
  }
}

extern "C" void kernel_launch(void* const* d_in, const int* in_sizes, int n_in,
                              void* d_out, int out_size, void* d_ws, size_t ws_size,
                              hipStream_t stream) {
  const float* x      = (const float*)d_in[0];
  const float* rev_w  = (const float*)d_in[1];
  const float* rev_b  = (const float*)d_in[2];
  const float* fc1_w  = (const float*)d_in[3];
  const float* fc1_b  = (const float*)d_in[4];
  const float* bn1_w  = (const float*)d_in[5];
  const float* bn1_b  = (const float*)d_in[6];
  const float* conv_w = (const float*)d_in[7];
  const float* conv_b = (const float*)d_in[8];
  const float* bn2_w  = (const float*)d_in[9];
  const float* bn2_b  = (const float*)d_in[10];
  const float* fc2_w  = (const float*)d_in[11];
  const float* fc2_b  = (const float*)d_in[12];
  const float* m1_w   = (const float*)d_in[13];
  const float* m1_b   = (const float*)d_in[14];
  const float* m2_w   = (const float*)d_in[15];
  const float* m2_b   = (const float*)d_in[16];
  const float* gl     = (const float*)d_in[17];
  const float* ln_w   = (const float*)d_in[18];
  const float* ln_b   = (const float*)d_in[19];
  const float* seas_w = (const float*)d_in[20];
  const float* seas_b = (const float*)d_in[21];
  const float* tr_w   = (const float*)d_in[22];
  const float* tr_b   = (const float*)d_in[23];
  const float* fus_w  = (const float*)d_in[24];
  const float* fus_b  = (const float*)d_in[25];
  float* out = (float*)d_out;
  float* ws = (float*)d_ws;

  __hip_bfloat16* Wsf  = (__hip_bfloat16*)(ws);
  __hip_bfloat16* Wtf  = (__hip_bfloat16*)(ws + 49152);
  float* biasc   = ws + 73728;
  float* colsumT = ws + 73856;
  float* scale1  = ws + 73984;
  float* shift1  = ws + 74048;
  float* scale2  = ws + 74112;
  float* shift2  = ws + 74176;
  float* partials= ws + 74240;
  float* rowpar  = ws + 238592;
  float* s_raw   = ws + 320768;
  __hip_bfloat16* t_bf = (__hip_bfloat16*)(ws + 11168000);
  __hip_bfloat16* ybf  = (__hip_bfloat16*)(ws + 16427264);

  hipLaunchKernelGGL(k0_fold,  dim3(576),  dim3(256), 0, stream, seas_w, tr_w, fus_w, Wsf, Wtf);
  hipLaunchKernelGGL(k0b_bias, dim3(1),    dim3(128), 0, stream, seas_b, tr_b, fus_w, fus_b, tr_w, biasc, colsumT);
  hipLaunchKernelGGL(k1_revin_ema, dim3(BC_/64), dim3(256), 0, stream, x, rev_w, rev_b, s_raw, t_bf, rowpar);
  hipLaunchKernelGGL(k2_bn1stats, dim3(NBLK2_), dim3(256), 0, stream, s_raw, rowpar, fc1_w, fc1_b, partials);
  hipLaunchKernelGGL(k_bnreduce, dim3(64), dim3(256), 0, stream, partials, NBLK2_, bn1_w, bn1_b, scale1, shift1);
  hipLaunchKernelGGL(k3_bn2stats, dim3(NBLK2_), dim3(256), 0, stream, s_raw, rowpar, fc1_w, fc1_b, scale1, shift1, conv_w, conv_b, partials);
  hipLaunchKernelGGL(k_bnreduce, dim3(64), dim3(256), 0, stream, partials, NBLK2_, bn2_w, bn2_b, scale2, shift2);
  hipLaunchKernelGGL(k5a_pipeline, dim3(BC_/RB_), dim3(256), 0, stream,
    s_raw, rowpar, fc1_w, fc1_b, scale1, shift1, conv_w, conv_b,
    scale2, shift2, fc2_w, fc2_b, m1_w, m1_b, m2_w, m2_b, gl, ln_w, ln_b, ybf);
  hipLaunchKernelGGL(k5b_gemm, dim3(BC_/64), dim3(256), 0, stream,
    ybf, t_bf, Wsf, Wtf, rowpar, rev_b, biasc, colsumT, out);
}

// Round 4
// 830.117 us; speedup vs baseline: 3.0128x; 3.0128x over previous
//
#include <hip/hip_runtime.h>
#include <hip/hip_bf16.h>
#include <math.h>

#define B_    64
#define L_    512
#define C_    321
#define PRED_ 96
#define N_    64
#define HID_  32
#define BC_   (B_*C_)   // 20544
#define SROW_ 528       // padded stride for seasonal rows (520 used)
#define EPS_  1e-5f
#define ALPHA_ 0.2f
#define GR_   16        // rows per block in bn-stat kernels
#define RB_   8         // rows per block in k5a
#define NBLK2_ (BC_/GR_) // 1284

typedef __attribute__((ext_vector_type(8))) short bf16x8;
typedef __attribute__((ext_vector_type(4))) float f32x4;

__device__ __forceinline__ float gelu_f(float x){
  return 0.5f*x*(1.0f + erff(x*0.70710678118654752440f));
}
__device__ __forceinline__ unsigned short bf16bits(float x){
  __hip_bfloat16 h = __float2bfloat16(x);
  return *(unsigned short*)&h;
}

// ---------- K0: fold seas/tr matmuls through fus; store bf16 col-major [j][k] ----------
__global__ __launch_bounds__(256) void k0_fold(
    const float* __restrict__ seas_w, const float* __restrict__ tr_w,
    const float* __restrict__ fus_w,
    __hip_bfloat16* __restrict__ Wsf, __hip_bfloat16* __restrict__ Wtf) {
  int idx = blockIdx.x*256 + threadIdx.x;
  if (idx >= 96*1536) return;
  int j = idx / 1536, k = idx - j*1536;
  float acc = 0.f;
  if (k < 1024) {
    for (int i=0;i<96;++i) acc = fmaf(fus_w[j*192+i], seas_w[i*1024+k], acc);
    Wsf[(size_t)j*1024 + k] = __float2bfloat16(acc);
  } else {
    int l = k - 1024;
    for (int i=0;i<96;++i) acc = fmaf(fus_w[j*192+96+i], tr_w[i*512+l], acc);
    Wtf[(size_t)j*512 + l] = __float2bfloat16(acc);
  }
}

// ---------- K0b: combined bias + column-sum of folded trend matrix ----------
__global__ void k0b_bias(
    const float* __restrict__ seas_b, const float* __restrict__ tr_b,
    const float* __restrict__ fus_w, const float* __restrict__ fus_b,
    const float* __restrict__ tr_w,
    float* __restrict__ biasc, float* __restrict__ colsumT) {
  __shared__ float rowsum[96];
  int t = threadIdx.x;
  if (t < 96) {
    float s = 0.f;
    for (int l=0;l<512;++l) s += tr_w[t*512+l];
    rowsum[t] = s;
  }
  __syncthreads();
  if (t < 96) {
    float acc = fus_b[t], cs = 0.f;
    for (int i=0;i<96;++i) {
      acc = fmaf(fus_w[t*192+i],    seas_b[i], acc);
      acc = fmaf(fus_w[t*192+96+i], tr_b[i],   acc);
      cs  = fmaf(fus_w[t*192+96+i], rowsum[i], cs);
    }
    biasc[t] = acc; colsumT[t] = cs;
  }
}

// ---------- K1: RevIN stats + chunked EMA scan (4 threads/row) ----------
__global__ __launch_bounds__(256) void k1_revin_ema(
    const float* __restrict__ x, const float* __restrict__ rev_w, const float* __restrict__ rev_b,
    float* __restrict__ s_raw, __hip_bfloat16* __restrict__ t_bf, float* __restrict__ rowpar) {
  __shared__ float lf[4][64];
  __shared__ float psum[4][64], psq[4][64];
  int tid = threadIdx.x;
  int q = tid >> 6, r = tid & 63;
  int row = blockIdx.x*64 + r;
  int b = row / C_, c = row - b*C_;
  const float* xp = x + (size_t)b*L_*C_ + c;
  int l0 = q*128;
  float tloc = 0.f, sum = 0.f, sq = 0.f;
  for (int i=0;i<128;++i) {
    float v = xp[(size_t)(l0+i)*C_];
    sum += v; sq = fmaf(v,v,sq);
    if (q==0 && i==0) tloc = v;
    else tloc = fmaf(ALPHA_, v, 0.8f*tloc);
  }
  lf[q][r] = tloc; psum[q][r] = sum; psq[q][r] = sq;
  __syncthreads();
  float cin = (q==0) ? 0.f : lf[q-1][r];
  if (q==0) {
    float S=0.f, Q=0.f;
    for (int qq=0;qq<4;++qq){ S += psum[qq][r]; Q += psq[qq][r]; }
    float mean = S*(1.0f/512.0f);
    float var  = (Q - S*S*(1.0f/512.0f))*(1.0f/511.0f);
    var = fmaxf(var, 0.f);
    float stdv = sqrtf(var) + EPS_;
    float rwc = rev_w[c], rbc = rev_b[c];
    float a = rwc / stdv;
    float g = rbc - mean*a;
    float inva = stdv / rwc;
    ((float4*)rowpar)[row] = make_float4(a, g, mean, inva);
  }
  float loc = 0.f, f = 1.f, vlast = 0.f, tlast = 0.f;
  for (int i=0;i<128;++i) {
    float v = xp[(size_t)(l0+i)*C_];
    if (q==0 && i==0) loc = v;
    else loc = fmaf(ALPHA_, v, 0.8f*loc);
    f *= 0.8f;
    float tt = fmaf(f, cin, loc);
    s_raw[(size_t)row*SROW_ + l0 + i] = v - tt;
    t_bf[(size_t)row*512 + l0 + i] = __float2bfloat16(tt);
    vlast = v; tlast = tt;
  }
  if (q==3) {
    float slast = vlast - tlast;
    for (int k=0;k<8;++k) s_raw[(size_t)row*SROW_ + 512 + k] = slast;
  }
}

// ---------- K2: BN1 statistics of gelu(fc1(sp)) ----------
__global__ __launch_bounds__(256) void k2_bn1stats(
    const float* __restrict__ s_raw, const float* __restrict__ rowpar,
    const float* __restrict__ fc1_w, const float* __restrict__ fc1_b,
    float* __restrict__ partials) {
  __shared__ float sl[GR_*SROW_];
  __shared__ float w1[512];
  __shared__ float b1[32];
  __shared__ float al[GR_];
  __shared__ float red[2][GR_*64];
  int t = threadIdx.x;
  int row0 = blockIdx.x*GR_;
  if (t < GR_) al[t] = rowpar[(size_t)(row0+t)*4];
  for (int idx=t; idx<512; idx+=256) w1[idx] = fc1_w[idx];
  if (t < 32) b1[t] = fc1_b[t];
  __syncthreads();
  for (int idx=t; idx<GR_*520; idx+=256) {
    int rr = idx/520, cc = idx - rr*520;
    sl[rr*SROW_+cc] = s_raw[(size_t)(row0+rr)*SROW_+cc] * al[rr];
  }
  __syncthreads();
  int lr = t >> 4, ng = t & 15;
  for (int q=0;q<4;++q) {
    int n = ng + 16*q;
    float sp[16];
    #pragma unroll
    for (int p=0;p<16;++p) sp[p] = sl[lr*SROW_ + n*8 + p];
    float s1=0.f, s2=0.f;
    #pragma unroll
    for (int hid=0; hid<32; ++hid) {
      float acc = b1[hid];
      #pragma unroll
      for (int p=0;p<16;++p) acc = fmaf(sp[p], w1[hid*16+p], acc);
      float gv = gelu_f(acc);
      s1 += gv; s2 = fmaf(gv,gv,s2);
    }
    red[0][lr*64+n] = s1;
    red[1][lr*64+n] = s2;
  }
  __syncthreads();
  if (t < 64) {
    float S1=0.f, S2=0.f;
    for (int lr2=0; lr2<GR_; ++lr2) { S1 += red[0][lr2*64+t]; S2 += red[1][lr2*64+t]; }
    partials[((size_t)blockIdx.x*64+t)*2+0] = S1;
    partials[((size_t)blockIdx.x*64+t)*2+1] = S2;
  }
}

// ---------- bn reduce ----------
__global__ __launch_bounds__(256) void k_bnreduce(
    const float* __restrict__ partials, int nblk,
    const float* __restrict__ bnw, const float* __restrict__ bnb,
    float* __restrict__ scale, float* __restrict__ shift) {
  __shared__ float red[2][256];
  int n = blockIdx.x, t = threadIdx.x;
  float s1=0.f, s2=0.f;
  for (int i=t; i<nblk; i+=256) {
    s1 += partials[((size_t)i*64+n)*2+0];
    s2 += partials[((size_t)i*64+n)*2+1];
  }
  red[0][t]=s1; red[1][t]=s2;
  __syncthreads();
  for (int off=128; off>0; off>>=1) {
    if (t<off) { red[0][t]+=red[0][t+off]; red[1][t]+=red[1][t+off]; }
    __syncthreads();
  }
  if (t==0) {
    const float count = (float)BC_ * 32.0f;
    float mu = red[0][0]/count;
    float var = red[1][0]/count - mu*mu;
    float sc = rsqrtf(var + EPS_) * bnw[n];
    scale[n] = sc;
    shift[n] = bnb[n] - mu*sc;
  }
}

// ---------- K3: BN2 statistics (h[32] then in-place conv) ----------
__global__ __launch_bounds__(256) void k3_bn2stats(
    const float* __restrict__ s_raw, const float* __restrict__ rowpar,
    const float* __restrict__ fc1_w, const float* __restrict__ fc1_b,
    const float* __restrict__ scale1, const float* __restrict__ shift1,
    const float* __restrict__ conv_w, const float* __restrict__ conv_b,
    float* __restrict__ partials) {
  __shared__ float sl[GR_*SROW_];
  __shared__ float w1[512];
  __shared__ float b1[32];
  __shared__ float al[GR_];
  __shared__ float sc1[64], sh1[64], cw[192], cb[64];
  __shared__ float red[2][GR_*64];
  int t = threadIdx.x;
  int row0 = blockIdx.x*GR_;
  if (t < GR_) al[t] = rowpar[(size_t)(row0+t)*4];
  for (int idx=t; idx<512; idx+=256) w1[idx] = fc1_w[idx];
  if (t < 32) b1[t] = fc1_b[t];
  if (t < 64) { sc1[t]=scale1[t]; sh1[t]=shift1[t]; cb[t]=conv_b[t]; }
  if (t >= 64 && t < 256) cw[t-64] = conv_w[t-64];
  __syncthreads();
  for (int idx=t; idx<GR_*520; idx+=256) {
    int rr = idx/520, cc = idx - rr*520;
    sl[rr*SROW_+cc] = s_raw[(size_t)(row0+rr)*SROW_+cc] * al[rr];
  }
  __syncthreads();
  int lr = t >> 4, ng = t & 15;
  for (int q=0;q<4;++q) {
    int n = ng + 16*q;
    float sp[16];
    #pragma unroll
    for (int p=0;p<16;++p) sp[p] = sl[lr*SROW_ + n*8 + p];
    float scn = sc1[n], shn = sh1[n];
    float h[32];
    #pragma unroll
    for (int hid=0; hid<32; ++hid) {
      float acc = b1[hid];
      #pragma unroll
      for (int p=0;p<16;++p) acc = fmaf(sp[p], w1[hid*16+p], acc);
      h[hid] = fmaf(gelu_f(acc), scn, shn);
    }
    float w0=cw[n*3], wm=cw[n*3+1], wpp=cw[n*3+2], cbn=cb[n];
    float s1=0.f, s2=0.f, prev=0.f;
    #pragma unroll
    for (int k2=0;k2<32;++k2) {
      float cur = h[k2];
      float cv = cbn;
      cv = fmaf(prev, w0, cv);
      cv = fmaf(cur, wm, cv);
      if (k2<31) cv = fmaf(h[k2+1], wpp, cv);
      float gv = gelu_f(cv);
      s1 += gv; s2 = fmaf(gv,gv,s2);
      prev = cur;
    }
    red[0][lr*64+n]=s1; red[1][lr*64+n]=s2;
  }
  __syncthreads();
  if (t < 64) {
    float S1=0.f, S2=0.f;
    for (int lr2=0; lr2<GR_; ++lr2) { S1 += red[0][lr2*64+t]; S2 += red[1][lr2*64+t]; }
    partials[((size_t)blockIdx.x*64+t)*2+0] = S1;
    partials[((size_t)blockIdx.x*64+t)*2+1] = S2;
  }
}

// ---------- K5a: per-row pipeline -> LayerNorm'd y (bf16) ----------
// Live-set-minimized: h[32] overwritten in place by conv stage (prev temp),
// sp re-read from LDS for the residual add. No min-occupancy bound.
__global__ __launch_bounds__(256) void k5a_pipeline(
    const float* __restrict__ s_raw, const float* __restrict__ rowpar,
    const float* __restrict__ fc1_w, const float* __restrict__ fc1_b,
    const float* __restrict__ scale1, const float* __restrict__ shift1,
    const float* __restrict__ conv_w, const float* __restrict__ conv_b,
    const float* __restrict__ scale2, const float* __restrict__ shift2,
    const float* __restrict__ fc2_w, const float* __restrict__ fc2_b,
    const float* __restrict__ m1_w, const float* __restrict__ m1_b,
    const float* __restrict__ m2_w, const float* __restrict__ m2_b,
    const float* __restrict__ gl_scale,
    const float* __restrict__ ln_w, const float* __restrict__ ln_b,
    __hip_bfloat16* __restrict__ ybf) {
  __shared__ float sl[RB_*SROW_];
  __shared__ float pl[RB_*64];
  __shared__ float hl[RB_*128];
  __shared__ float wl[RB_*64];
  __shared__ float rp[RB_];
  __shared__ float w1[512], b1[32], cw[192], cb[64];
  __shared__ float sc1[64], sh1[64], sc2[64], sh2[64];
  __shared__ float w2s[512], b2s[16], lnw[16], lnb[16];
  int t = threadIdx.x;
  int row0 = blockIdx.x*RB_;
  if (t < RB_) rp[t] = rowpar[(size_t)(row0+t)*4];
  for (int idx=t; idx<512; idx+=256) { w1[idx]=fc1_w[idx]; w2s[idx]=fc2_w[idx]; }
  if (t<32) b1[t]=fc1_b[t];
  if (t<16) { b2s[t]=fc2_b[t]; lnw[t]=ln_w[t]; lnb[t]=ln_b[t]; }
  if (t<64) { sc1[t]=scale1[t]; sh1[t]=shift1[t]; sc2[t]=scale2[t]; sh2[t]=shift2[t]; cb[t]=conv_b[t]; }
  if (t>=64 && t<256) cw[t-64]=conv_w[t-64];
  __syncthreads();
  for (int idx=t; idx<RB_*520; idx+=256) {
    int rr = idx/520, cc = idx - rr*520;
    sl[rr*SROW_+cc] = s_raw[(size_t)(row0+rr)*SROW_+cc] * rp[rr];
  }
  __syncthreads();
  float glv = gl_scale[0];
  // P1: pooled
  for (int idx=t; idx<RB_*64; idx+=256) {
    int rr = idx>>6, n = idx&63;
    float s=0.f;
    #pragma unroll
    for (int p=0;p<16;++p) s += sl[rr*SROW_ + n*8 + p];
    pl[idx] = s*(1.0f/16.0f);
  }
  __syncthreads();
  // P2: hidden = gelu(m1 @ pooled + b)
  for (int idx=t; idx<RB_*128; idx+=256) {
    int rr = idx>>7, i = idx&127;
    float acc = m1_b[i];
    for (int k2=0;k2<64;++k2) acc = fmaf(pl[rr*64+k2], m1_w[i*64+k2], acc);
    hl[idx] = gelu_f(acc);
  }
  __syncthreads();
  // P3: w = sigmoid(m2 @ hidden + b)
  for (int idx=t; idx<RB_*64; idx+=256) {
    int rr = idx>>6, n = idx&63;
    float acc = m2_b[n];
    for (int k2=0;k2<128;++k2) acc = fmaf(hl[rr*128+k2], m2_w[n*128+k2], acc);
    wl[idx] = 1.0f/(1.0f + expf(-acc));
  }
  __syncthreads();
  // P4: per-(row,n) pipeline
  for (int idx=t; idx<RB_*64; idx+=256) {
    int rr = idx>>6, n = idx&63;
    // stage 1: fc1 + gelu + bn1  (live: sp16 + h32)
    float h[32];
    {
      float sp[16];
      #pragma unroll
      for (int p=0;p<16;++p) sp[p] = sl[rr*SROW_ + n*8 + p];
      float scn=sc1[n], shn=sh1[n];
      #pragma unroll
      for (int hid=0;hid<32;++hid) {
        float acc=b1[hid];
        #pragma unroll
        for (int p=0;p<16;++p) acc=fmaf(sp[p], w1[hid*16+p], acc);
        h[hid]=fmaf(gelu_f(acc), scn, shn);
      }
    }
    // stage 2: in-place conv + gelu + bn2  (live: h32 + 3 temps)
    {
      float w0=cw[n*3], wm=cw[n*3+1], wpp=cw[n*3+2], cbn=cb[n];
      float sc2n=sc2[n], sh2n=sh2[n];
      float prev=0.f;
      #pragma unroll
      for (int k2=0;k2<32;++k2) {
        float cur = h[k2];
        float cv = cbn;
        cv = fmaf(prev, w0, cv);
        cv = fmaf(cur, wm, cv);
        if (k2<31) cv = fmaf(h[k2+1], wpp, cv);
        h[k2] = fmaf(gelu_f(cv), sc2n, sh2n);
        prev = cur;
      }
    }
    // stage 3: fc2 accumulate  (live: h32 + yv16)
    float yv[16];
    #pragma unroll
    for (int p=0;p<16;++p) {
      float acc=b2s[p];
      #pragma unroll
      for (int hid=0;hid<32;++hid) acc=fmaf(h[hid], w2s[p*32+hid], acc);
      yv[p]=acc;
    }
    // stage 4: residual (sp from LDS) + LN + packed bf16 store
    float smul = 3.0f + glv*wl[idx];
    float mu=0.f;
    #pragma unroll
    for (int p=0;p<16;++p) {
      yv[p]=fmaf(sl[rr*SROW_ + n*8 + p], smul, yv[p]);
      mu+=yv[p];
    }
    mu *= (1.0f/16.0f);
    float var=0.f;
    #pragma unroll
    for (int p=0;p<16;++p){ float d=yv[p]-mu; var=fmaf(d,d,var); }
    var *= (1.0f/16.0f);
    float rs = rsqrtf(var + EPS_);
    unsigned int wds[8];
    #pragma unroll
    for (int j=0;j<8;++j) {
      unsigned int lo = bf16bits(fmaf((yv[2*j]-mu)*rs,   lnw[2*j],   lnb[2*j]));
      unsigned int hi = bf16bits(fmaf((yv[2*j+1]-mu)*rs, lnw[2*j+1], lnb[2*j+1]));
      wds[j] = lo | (hi<<16);
    }
    size_t ybase = (size_t)(row0+rr)*1024 + n*16;
    uint4* dst = (uint4*)&ybf[ybase];
    dst[0] = make_uint4(wds[0],wds[1],wds[2],wds[3]);
    dst[1] = make_uint4(wds[4],wds[5],wds[6],wds[7]);
  }
}

// ---------- K5b: bf16 MFMA GEMM  out = y@Wsf^T + a*(t@Wtf^T) + g*colsum + biasc ----------
__global__ __launch_bounds__(256) void k5b_gemm(
    const __hip_bfloat16* __restrict__ ybf, const __hip_bfloat16* __restrict__ tbf,
    const __hip_bfloat16* __restrict__ Wsf, const __hip_bfloat16* __restrict__ Wtf,
    const float* __restrict__ rowpar, const float* __restrict__ rev_b,
    const float* __restrict__ biasc, const float* __restrict__ colsumT,
    float* __restrict__ out) {
  __shared__ __align__(16) __hip_bfloat16 As[64*72];
  __shared__ __align__(16) __hip_bfloat16 Bs[96*72];
  __shared__ float rp[256];
  __shared__ float rbl[64];
  __shared__ int   obase[64];
  __shared__ float bcl[96], csl[96];
  int tid = threadIdx.x;
  int row0 = blockIdx.x*64;
  rp[tid] = rowpar[(size_t)row0*4 + tid];
  if (tid < 64) {
    int row = row0 + tid; int b = row/C_; int c = row - b*C_;
    rbl[tid] = rev_b[c]; obase[tid] = b*PRED_*C_ + c;
  }
  if (tid >= 128 && tid < 224) { bcl[tid-128]=biasc[tid-128]; csl[tid-128]=colsumT[tid-128]; }
  int lane = tid & 63, w = tid >> 6;
  int fr = lane & 15, fg = lane >> 4;
  f32x4 acc[6];
  #pragma unroll
  for (int n=0;n<6;++n) acc[n] = (f32x4){0.f,0.f,0.f,0.f};
  // ---- trend phase: K=512 ----
  for (int ks=0; ks<8; ++ks) {
    __syncthreads();
    #pragma unroll
    for (int u=0;u<2;++u) {
      int i = tid + u*256; int rr = i>>3, ch = i&7;
      *(uint4*)&As[rr*72 + ch*8] = *(const uint4*)&tbf[(size_t)(row0+rr)*512 + ks*64 + ch*8];
    }
    #pragma unroll
    for (int u=0;u<3;++u) {
      int i = tid + u*256; int rr = i>>3, ch = i&7;
      *(uint4*)&Bs[rr*72 + ch*8] = *(const uint4*)&Wtf[(size_t)rr*512 + ks*64 + ch*8];
    }
    __syncthreads();
    #pragma unroll
    for (int ksub=0; ksub<2; ++ksub) {
      bf16x8 av = *(bf16x8*)&As[(w*16+fr)*72 + ksub*32 + fg*8];
      #pragma unroll
      for (int n=0;n<6;++n) {
        bf16x8 bv = *(bf16x8*)&Bs[(n*16+fr)*72 + ksub*32 + fg*8];
        acc[n] = __builtin_amdgcn_mfma_f32_16x16x32_bf16(av, bv, acc[n], 0,0,0);
      }
    }
  }
  #pragma unroll
  for (int n=0;n<6;++n) {
    #pragma unroll
    for (int reg=0;reg<4;++reg) {
      int rloc = w*16 + fg*4 + reg;
      acc[n][reg] *= rp[rloc*4+0];
    }
  }
  // ---- seasonal phase: K=1024 ----
  for (int ks=0; ks<16; ++ks) {
    __syncthreads();
    #pragma unroll
    for (int u=0;u<2;++u) {
      int i = tid + u*256; int rr = i>>3, ch = i&7;
      *(uint4*)&As[rr*72 + ch*8] = *(const uint4*)&ybf[(size_t)(row0+rr)*1024 + ks*64 + ch*8];
    }
    #pragma unroll
    for (int u=0;u<3;++u) {
      int i = tid + u*256; int rr = i>>3, ch = i&7;
      *(uint4*)&Bs[rr*72 + ch*8] = *(const uint4*)&Wsf[(size_t)rr*1024 + ks*64 + ch*8];
    }
    __syncthreads();
    #pragma unroll
    for (int ksub=0; ksub<2; ++ksub) {
      bf16x8 av = *(bf16x8*)&As[(w*16+fr)*72 + ksub*32 + fg*8];
      #pragma unroll
      for (int n=0;n<6;++n) {
        bf16x8 bv = *(bf16x8*)&Bs[(n*16+fr)*72 + ksub*32 + fg*8];
        acc[n] = __builtin_amdgcn_mfma_f32_16x16x32_bf16(av, bv, acc[n], 0,0,0);
      }
    }
  }
  #pragma unroll
  for (int n=0;n<6;++n) {
    int col = n*16 + fr;
    float cs = csl[col], bc = bcl[col];
    #pragma unroll
    for (int reg=0;reg<4;++reg) {
      int rloc = w*16 + fg*4 + reg;
      float g = rp[rloc*4+1], meanv = rp[rloc*4+2], inva = rp[rloc*4+3];
      float val = acc[n][reg] + g*cs + bc;
      val = (val - rbl[rloc])*inva + meanv;
      out[(size_t)obase[rloc] + (size_t)col*C_] = val;
    }
  }
}

extern "C" void kernel_launch(void* const* d_in, const int* in_sizes, int n_in,
                              void* d_out, int out_size, void* d_ws, size_t ws_size,
                              hipStream_t stream) {
  const float* x      = (const float*)d_in[0];
  const float* rev_w  = (const float*)d_in[1];
  const float* rev_b  = (const float*)d_in[2];
  const float* fc1_w  = (const float*)d_in[3];
  const float* fc1_b  = (const float*)d_in[4];
  const float* bn1_w  = (const float*)d_in[5];
  const float* bn1_b  = (const float*)d_in[6];
  const float* conv_w = (const float*)d_in[7];
  const float* conv_b = (const float*)d_in[8];
  const float* bn2_w  = (const float*)d_in[9];
  const float* bn2_b  = (const float*)d_in[10];
  const float* fc2_w  = (const float*)d_in[11];
  const float* fc2_b  = (const float*)d_in[12];
  const float* m1_w   = (const float*)d_in[13];
  const float* m1_b   = (const float*)d_in[14];
  const float* m2_w   = (const float*)d_in[15];
  const float* m2_b   = (const float*)d_in[16];
  const float* gl     = (const float*)d_in[17];
  const float* ln_w   = (const float*)d_in[18];
  const float* ln_b   = (const float*)d_in[19];
  const float* seas_w = (const float*)d_in[20];
  const float* seas_b = (const float*)d_in[21];
  const float* tr_w   = (const float*)d_in[22];
  const float* tr_b   = (const float*)d_in[23];
  const float* fus_w  = (const float*)d_in[24];
  const float* fus_b  = (const float*)d_in[25];
  float* out = (float*)d_out;
  float* ws = (float*)d_ws;

  __hip_bfloat16* Wsf  = (__hip_bfloat16*)(ws);
  __hip_bfloat16* Wtf  = (__hip_bfloat16*)(ws + 49152);
  float* biasc   = ws + 73728;
  float* colsumT = ws + 73856;
  float* scale1  = ws + 73984;
  float* shift1  = ws + 74048;
  float* scale2  = ws + 74112;
  float* shift2  = ws + 74176;
  float* partials= ws + 74240;
  float* rowpar  = ws + 238592;
  float* s_raw   = ws + 320768;
  __hip_bfloat16* t_bf = (__hip_bfloat16*)(ws + 11168000);
  __hip_bfloat16* ybf  = (__hip_bfloat16*)(ws + 16427264);

  hipLaunchKernelGGL(k0_fold,  dim3(576),  dim3(256), 0, stream, seas_w, tr_w, fus_w, Wsf, Wtf);
  hipLaunchKernelGGL(k0b_bias, dim3(1),    dim3(128), 0, stream, seas_b, tr_b, fus_w, fus_b, tr_w, biasc, colsumT);
  hipLaunchKernelGGL(k1_revin_ema, dim3(BC_/64), dim3(256), 0, stream, x, rev_w, rev_b, s_raw, t_bf, rowpar);
  hipLaunchKernelGGL(k2_bn1stats, dim3(NBLK2_), dim3(256), 0, stream, s_raw, rowpar, fc1_w, fc1_b, partials);
  hipLaunchKernelGGL(k_bnreduce, dim3(64), dim3(256), 0, stream, partials, NBLK2_, bn1_w, bn1_b, scale1, shift1);
  hipLaunchKernelGGL(k3_bn2stats, dim3(NBLK2_), dim3(256), 0, stream, s_raw, rowpar, fc1_w, fc1_b, scale1, shift1, conv_w, conv_b, partials);
  hipLaunchKernelGGL(k_bnreduce, dim3(64), dim3(256), 0, stream, partials, NBLK2_, bn2_w, bn2_b, scale2, shift2);
  hipLaunchKernelGGL(k5a_pipeline, dim3(BC_/RB_), dim3(256), 0, stream,
    s_raw, rowpar, fc1_w, fc1_b, scale1, shift1, conv_w, conv_b,
    scale2, shift2, fc2_w, fc2_b, m1_w, m1_b, m2_w, m2_b, gl, ln_w, ln_b, ybf);
  hipLaunchKernelGGL(k5b_gemm, dim3(BC_/64), dim3(256), 0, stream,
    ybf, t_bf, Wsf, Wtf, rowpar, rev_b, biasc, colsumT, out);
}

// Round 5
// 599.985 us; speedup vs baseline: 4.1684x; 1.3836x over previous
//
#include <hip/hip_runtime.h>
#include <hip/hip_bf16.h>
#include <math.h>

#define B_    64
#define L_    512
#define C_    321
#define PRED_ 96
#define N_    64
#define HID_  32
#define BC_   (B_*C_)   // 20544
#define SROW_ 528       // padded stride for seasonal rows (520 used)
#define EPS_  1e-5f
#define ALPHA_ 0.2f
#define GR_   16        // rows per block in bn-stat kernels
#define RB_   8         // rows per block in k5a
#define NBLK2_ (BC_/GR_) // 1284

typedef __attribute__((ext_vector_type(8))) short bf16x8;
typedef __attribute__((ext_vector_type(4))) float f32x4;

__device__ __forceinline__ float gelu_f(float x){
  return 0.5f*x*(1.0f + erff(x*0.70710678118654752440f));
}
__device__ __forceinline__ unsigned short bf16bits(float x){
  __hip_bfloat16 h = __float2bfloat16(x);
  return *(unsigned short*)&h;
}

// ---------- K0: fold seas/tr matmuls through fus; store bf16 col-major [j][k] ----------
__global__ __launch_bounds__(256) void k0_fold(
    const float* __restrict__ seas_w, const float* __restrict__ tr_w,
    const float* __restrict__ fus_w,
    __hip_bfloat16* __restrict__ Wsf, __hip_bfloat16* __restrict__ Wtf) {
  int idx = blockIdx.x*256 + threadIdx.x;
  if (idx >= 96*1536) return;
  int j = idx / 1536, k = idx - j*1536;
  float acc = 0.f;
  if (k < 1024) {
    for (int i=0;i<96;++i) acc = fmaf(fus_w[j*192+i], seas_w[i*1024+k], acc);
    Wsf[(size_t)j*1024 + k] = __float2bfloat16(acc);
  } else {
    int l = k - 1024;
    for (int i=0;i<96;++i) acc = fmaf(fus_w[j*192+96+i], tr_w[i*512+l], acc);
    Wtf[(size_t)j*512 + l] = __float2bfloat16(acc);
  }
}

// ---------- K0b: combined bias + column-sum of folded trend matrix ----------
__global__ void k0b_bias(
    const float* __restrict__ seas_b, const float* __restrict__ tr_b,
    const float* __restrict__ fus_w, const float* __restrict__ fus_b,
    const float* __restrict__ tr_w,
    float* __restrict__ biasc, float* __restrict__ colsumT) {
  __shared__ float rowsum[96];
  int t = threadIdx.x;
  if (t < 96) {
    float s = 0.f;
    for (int l=0;l<512;++l) s += tr_w[t*512+l];
    rowsum[t] = s;
  }
  __syncthreads();
  if (t < 96) {
    float acc = fus_b[t], cs = 0.f;
    for (int i=0;i<96;++i) {
      acc = fmaf(fus_w[t*192+i],    seas_b[i], acc);
      acc = fmaf(fus_w[t*192+96+i], tr_b[i],   acc);
      cs  = fmaf(fus_w[t*192+96+i], rowsum[i], cs);
    }
    biasc[t] = acc; colsumT[t] = cs;
  }
}

// ---------- K1: RevIN stats + chunked EMA scan (4 threads/row) ----------
__global__ __launch_bounds__(256) void k1_revin_ema(
    const float* __restrict__ x, const float* __restrict__ rev_w, const float* __restrict__ rev_b,
    float* __restrict__ s_raw, __hip_bfloat16* __restrict__ t_bf, float* __restrict__ rowpar) {
  __shared__ float lf[4][64];
  __shared__ float psum[4][64], psq[4][64];
  int tid = threadIdx.x;
  int q = tid >> 6, r = tid & 63;
  int row = blockIdx.x*64 + r;
  int b = row / C_, c = row - b*C_;
  const float* xp = x + (size_t)b*L_*C_ + c;
  int l0 = q*128;
  float tloc = 0.f, sum = 0.f, sq = 0.f;
  for (int i=0;i<128;++i) {
    float v = xp[(size_t)(l0+i)*C_];
    sum += v; sq = fmaf(v,v,sq);
    if (q==0 && i==0) tloc = v;
    else tloc = fmaf(ALPHA_, v, 0.8f*tloc);
  }
  lf[q][r] = tloc; psum[q][r] = sum; psq[q][r] = sq;
  __syncthreads();
  float cin = (q==0) ? 0.f : lf[q-1][r];
  if (q==0) {
    float S=0.f, Q=0.f;
    for (int qq=0;qq<4;++qq){ S += psum[qq][r]; Q += psq[qq][r]; }
    float mean = S*(1.0f/512.0f);
    float var  = (Q - S*S*(1.0f/512.0f))*(1.0f/511.0f);
    var = fmaxf(var, 0.f);
    float stdv = sqrtf(var) + EPS_;
    float rwc = rev_w[c], rbc = rev_b[c];
    float a = rwc / stdv;
    float g = rbc - mean*a;
    float inva = stdv / rwc;
    ((float4*)rowpar)[row] = make_float4(a, g, mean, inva);
  }
  float loc = 0.f, f = 1.f, vlast = 0.f, tlast = 0.f;
  for (int i=0;i<128;++i) {
    float v = xp[(size_t)(l0+i)*C_];
    if (q==0 && i==0) loc = v;
    else loc = fmaf(ALPHA_, v, 0.8f*loc);
    f *= 0.8f;
    float tt = fmaf(f, cin, loc);
    s_raw[(size_t)row*SROW_ + l0 + i] = v - tt;
    t_bf[(size_t)row*512 + l0 + i] = __float2bfloat16(tt);
    vlast = v; tlast = tt;
  }
  if (q==3) {
    float slast = vlast - tlast;
    for (int k=0;k<8;++k) s_raw[(size_t)row*SROW_ + 512 + k] = slast;
  }
}

// ---------- K2: BN1 statistics of gelu(fc1(sp)) — weights via scalar path ----------
__global__ __launch_bounds__(256) void k2_bn1stats(
    const float* __restrict__ s_raw, const float* __restrict__ rowpar,
    const float* __restrict__ fc1_w, const float* __restrict__ fc1_b,
    float* __restrict__ partials) {
  __shared__ float sl[GR_*SROW_];
  __shared__ float al[GR_];
  __shared__ float red[2][GR_*64];
  int t = threadIdx.x;
  int row0 = blockIdx.x*GR_;
  if (t < GR_) al[t] = rowpar[(size_t)(row0+t)*4];
  __syncthreads();
  for (int idx=t; idx<GR_*520; idx+=256) {
    int rr = idx/520, cc = idx - rr*520;
    sl[rr*SROW_+cc] = s_raw[(size_t)(row0+rr)*SROW_+cc] * al[rr];
  }
  __syncthreads();
  int lr = t >> 4, ng = t & 15;
  for (int q=0;q<4;++q) {
    int n = ng + 16*q;
    float sp[16];
    #pragma unroll
    for (int p=0;p<16;++p) sp[p] = sl[lr*SROW_ + n*8 + p];
    float s1=0.f, s2=0.f;
    #pragma unroll
    for (int hid=0; hid<32; ++hid) {
      float acc = fc1_b[hid];
      #pragma unroll
      for (int p=0;p<16;++p) acc = fmaf(sp[p], fc1_w[hid*16+p], acc);
      float gv = gelu_f(acc);
      s1 += gv; s2 = fmaf(gv,gv,s2);
    }
    red[0][lr*64+n] = s1;
    red[1][lr*64+n] = s2;
  }
  __syncthreads();
  if (t < 64) {
    float S1=0.f, S2=0.f;
    for (int lr2=0; lr2<GR_; ++lr2) { S1 += red[0][lr2*64+t]; S2 += red[1][lr2*64+t]; }
    partials[((size_t)blockIdx.x*64+t)*2+0] = S1;
    partials[((size_t)blockIdx.x*64+t)*2+1] = S2;
  }
}

// ---------- bn reduce ----------
__global__ __launch_bounds__(256) void k_bnreduce(
    const float* __restrict__ partials, int nblk,
    const float* __restrict__ bnw, const float* __restrict__ bnb,
    float* __restrict__ scale, float* __restrict__ shift) {
  __shared__ float red[2][256];
  int n = blockIdx.x, t = threadIdx.x;
  float s1=0.f, s2=0.f;
  for (int i=t; i<nblk; i+=256) {
    s1 += partials[((size_t)i*64+n)*2+0];
    s2 += partials[((size_t)i*64+n)*2+1];
  }
  red[0][t]=s1; red[1][t]=s2;
  __syncthreads();
  for (int off=128; off>0; off>>=1) {
    if (t<off) { red[0][t]+=red[0][t+off]; red[1][t]+=red[1][t+off]; }
    __syncthreads();
  }
  if (t==0) {
    const float count = (float)BC_ * 32.0f;
    float mu = red[0][0]/count;
    float var = red[1][0]/count - mu*mu;
    float sc = rsqrtf(var + EPS_) * bnw[n];
    scale[n] = sc;
    shift[n] = bnb[n] - mu*sc;
  }
}

// ---------- K3: BN2 statistics (in-place conv; weights via scalar path) ----------
__global__ __launch_bounds__(256) void k3_bn2stats(
    const float* __restrict__ s_raw, const float* __restrict__ rowpar,
    const float* __restrict__ fc1_w, const float* __restrict__ fc1_b,
    const float* __restrict__ scale1, const float* __restrict__ shift1,
    const float* __restrict__ conv_w, const float* __restrict__ conv_b,
    float* __restrict__ partials) {
  __shared__ float sl[GR_*SROW_];
  __shared__ float al[GR_];
  __shared__ float sc1[64], sh1[64], cw[192], cb[64];
  __shared__ float red[2][GR_*64];
  int t = threadIdx.x;
  int row0 = blockIdx.x*GR_;
  if (t < GR_) al[t] = rowpar[(size_t)(row0+t)*4];
  if (t < 64) { sc1[t]=scale1[t]; sh1[t]=shift1[t]; cb[t]=conv_b[t]; }
  if (t >= 64 && t < 256) cw[t-64] = conv_w[t-64];
  __syncthreads();
  for (int idx=t; idx<GR_*520; idx+=256) {
    int rr = idx/520, cc = idx - rr*520;
    sl[rr*SROW_+cc] = s_raw[(size_t)(row0+rr)*SROW_+cc] * al[rr];
  }
  __syncthreads();
  int lr = t >> 4, ng = t & 15;
  for (int q=0;q<4;++q) {
    int n = ng + 16*q;
    float sp[16];
    #pragma unroll
    for (int p=0;p<16;++p) sp[p] = sl[lr*SROW_ + n*8 + p];
    float scn = sc1[n], shn = sh1[n];
    float h[32];
    #pragma unroll
    for (int hid=0; hid<32; ++hid) {
      float acc = fc1_b[hid];
      #pragma unroll
      for (int p=0;p<16;++p) acc = fmaf(sp[p], fc1_w[hid*16+p], acc);
      h[hid] = fmaf(gelu_f(acc), scn, shn);
    }
    float w0=cw[n*3], wm=cw[n*3+1], wpp=cw[n*3+2], cbn=cb[n];
    float s1=0.f, s2=0.f, prev=0.f;
    #pragma unroll
    for (int k2=0;k2<32;++k2) {
      float cur = h[k2];
      float cv = cbn;
      cv = fmaf(prev, w0, cv);
      cv = fmaf(cur, wm, cv);
      if (k2<31) cv = fmaf(h[k2+1], wpp, cv);
      float gv = gelu_f(cv);
      s1 += gv; s2 = fmaf(gv,gv,s2);
      prev = cur;
    }
    red[0][lr*64+n]=s1; red[1][lr*64+n]=s2;
  }
  __syncthreads();
  if (t < 64) {
    float S1=0.f, S2=0.f;
    for (int lr2=0; lr2<GR_; ++lr2) { S1 += red[0][lr2*64+t]; S2 += red[1][lr2*64+t]; }
    partials[((size_t)blockIdx.x*64+t)*2+0] = S1;
    partials[((size_t)blockIdx.x*64+t)*2+1] = S2;
  }
}

// ---------- K5a: per-row pipeline -> LayerNorm'd y (bf16) ----------
// Wave-uniform weights (fc1_w/fc1_b/fc2_w/fc2_b/ln_w/ln_b) read via the
// scalar path (global + uniform index -> s_load + SGPR-operand fma);
// only thread-varying tables and the data tile live in LDS.
__global__ __launch_bounds__(256) void k5a_pipeline(
    const float* __restrict__ s_raw, const float* __restrict__ rowpar,
    const float* __restrict__ fc1_w, const float* __restrict__ fc1_b,
    const float* __restrict__ scale1, const float* __restrict__ shift1,
    const float* __restrict__ conv_w, const float* __restrict__ conv_b,
    const float* __restrict__ scale2, const float* __restrict__ shift2,
    const float* __restrict__ fc2_w, const float* __restrict__ fc2_b,
    const float* __restrict__ m1_w, const float* __restrict__ m1_b,
    const float* __restrict__ m2_w, const float* __restrict__ m2_b,
    const float* __restrict__ gl_scale,
    const float* __restrict__ ln_w, const float* __restrict__ ln_b,
    __hip_bfloat16* __restrict__ ybf) {
  __shared__ float sl[RB_*SROW_];
  __shared__ float pl[RB_*64];
  __shared__ float hl[RB_*128];
  __shared__ float wl[RB_*64];
  __shared__ float rp[RB_];
  __shared__ float cw[192], cb[64];
  __shared__ float sc1[64], sh1[64], sc2[64], sh2[64];
  int t = threadIdx.x;
  int row0 = blockIdx.x*RB_;
  if (t < RB_) rp[t] = rowpar[(size_t)(row0+t)*4];
  if (t<64) { sc1[t]=scale1[t]; sh1[t]=shift1[t]; sc2[t]=scale2[t]; sh2[t]=shift2[t]; cb[t]=conv_b[t]; }
  if (t>=64 && t<256) cw[t-64]=conv_w[t-64];
  __syncthreads();
  for (int idx=t; idx<RB_*520; idx+=256) {
    int rr = idx/520, cc = idx - rr*520;
    sl[rr*SROW_+cc] = s_raw[(size_t)(row0+rr)*SROW_+cc] * rp[rr];
  }
  __syncthreads();
  float glv = gl_scale[0];
  // P1: pooled
  for (int idx=t; idx<RB_*64; idx+=256) {
    int rr = idx>>6, n = idx&63;
    float s=0.f;
    #pragma unroll
    for (int p=0;p<16;++p) s += sl[rr*SROW_ + n*8 + p];
    pl[idx] = s*(1.0f/16.0f);
  }
  __syncthreads();
  // P2: hidden = gelu(m1 @ pooled + b)
  for (int idx=t; idx<RB_*128; idx+=256) {
    int rr = idx>>7, i = idx&127;
    float acc = m1_b[i];
    for (int k2=0;k2<64;++k2) acc = fmaf(pl[rr*64+k2], m1_w[i*64+k2], acc);
    hl[idx] = gelu_f(acc);
  }
  __syncthreads();
  // P3: w = sigmoid(m2 @ hidden + b)
  for (int idx=t; idx<RB_*64; idx+=256) {
    int rr = idx>>6, n = idx&63;
    float acc = m2_b[n];
    for (int k2=0;k2<128;++k2) acc = fmaf(hl[rr*128+k2], m2_w[n*128+k2], acc);
    wl[idx] = 1.0f/(1.0f + expf(-acc));
  }
  __syncthreads();
  // P4: per-(row,n) pipeline
  for (int idx=t; idx<RB_*64; idx+=256) {
    int rr = idx>>6, n = idx&63;
    // stage 1: fc1 + gelu + bn1
    float h[32];
    {
      float sp[16];
      #pragma unroll
      for (int p=0;p<16;++p) sp[p] = sl[rr*SROW_ + n*8 + p];
      float scn=sc1[n], shn=sh1[n];
      #pragma unroll
      for (int hid=0;hid<32;++hid) {
        float acc=fc1_b[hid];
        #pragma unroll
        for (int p=0;p<16;++p) acc=fmaf(sp[p], fc1_w[hid*16+p], acc);
        h[hid]=fmaf(gelu_f(acc), scn, shn);
      }
    }
    // stage 2: in-place conv + gelu + bn2
    {
      float w0=cw[n*3], wm=cw[n*3+1], wpp=cw[n*3+2], cbn=cb[n];
      float sc2n=sc2[n], sh2n=sh2[n];
      float prev=0.f;
      #pragma unroll
      for (int k2=0;k2<32;++k2) {
        float cur = h[k2];
        float cv = cbn;
        cv = fmaf(prev, w0, cv);
        cv = fmaf(cur, wm, cv);
        if (k2<31) cv = fmaf(h[k2+1], wpp, cv);
        h[k2] = fmaf(gelu_f(cv), sc2n, sh2n);
        prev = cur;
      }
    }
    // stage 3: fc2 accumulate
    float yv[16];
    #pragma unroll
    for (int p=0;p<16;++p) {
      float acc=fc2_b[p];
      #pragma unroll
      for (int hid=0;hid<32;++hid) acc=fmaf(h[hid], fc2_w[p*32+hid], acc);
      yv[p]=acc;
    }
    // stage 4: residual (sp from LDS) + LN + packed bf16 store
    float smul = 3.0f + glv*wl[idx];
    float mu=0.f;
    #pragma unroll
    for (int p=0;p<16;++p) {
      yv[p]=fmaf(sl[rr*SROW_ + n*8 + p], smul, yv[p]);
      mu+=yv[p];
    }
    mu *= (1.0f/16.0f);
    float var=0.f;
    #pragma unroll
    for (int p=0;p<16;++p){ float d=yv[p]-mu; var=fmaf(d,d,var); }
    var *= (1.0f/16.0f);
    float rs = rsqrtf(var + EPS_);
    unsigned int wds[8];
    #pragma unroll
    for (int j=0;j<8;++j) {
      unsigned int lo = bf16bits(fmaf((yv[2*j]-mu)*rs,   ln_w[2*j],   ln_b[2*j]));
      unsigned int hi = bf16bits(fmaf((yv[2*j+1]-mu)*rs, ln_w[2*j+1], ln_b[2*j+1]));
      wds[j] = lo | (hi<<16);
    }
    size_t ybase = (size_t)(row0+rr)*1024 + n*16;
    uint4* dst = (uint4*)&ybf[ybase];
    dst[0] = make_uint4(wds[0],wds[1],wds[2],wds[3]);
    dst[1] = make_uint4(wds[4],wds[5],wds[6],wds[7]);
  }
}

// ---------- K5b: bf16 MFMA GEMM  out = y@Wsf^T + a*(t@Wtf^T) + g*colsum + biasc ----------
__global__ __launch_bounds__(256) void k5b_gemm(
    const __hip_bfloat16* __restrict__ ybf, const __hip_bfloat16* __restrict__ tbf,
    const __hip_bfloat16* __restrict__ Wsf, const __hip_bfloat16* __restrict__ Wtf,
    const float* __restrict__ rowpar, const float* __restrict__ rev_b,
    const float* __restrict__ biasc, const float* __restrict__ colsumT,
    float* __restrict__ out) {
  __shared__ __align__(16) __hip_bfloat16 As[64*72];
  __shared__ __align__(16) __hip_bfloat16 Bs[96*72];
  __shared__ float rp[256];
  __shared__ float rbl[64];
  __shared__ int   obase[64];
  __shared__ float bcl[96], csl[96];
  int tid = threadIdx.x;
  int row0 = blockIdx.x*64;
  rp[tid] = rowpar[(size_t)row0*4 + tid];
  if (tid < 64) {
    int row = row0 + tid; int b = row/C_; int c = row - b*C_;
    rbl[tid] = rev_b[c]; obase[tid] = b*PRED_*C_ + c;
  }
  if (tid >= 128 && tid < 224) { bcl[tid-128]=biasc[tid-128]; csl[tid-128]=colsumT[tid-128]; }
  int lane = tid & 63, w = tid >> 6;
  int fr = lane & 15, fg = lane >> 4;
  f32x4 acc[6];
  #pragma unroll
  for (int n=0;n<6;++n) acc[n] = (f32x4){0.f,0.f,0.f,0.f};
  // ---- trend phase: K=512 ----
  for (int ks=0; ks<8; ++ks) {
    __syncthreads();
    #pragma unroll
    for (int u=0;u<2;++u) {
      int i = tid + u*256; int rr = i>>3, ch = i&7;
      *(uint4*)&As[rr*72 + ch*8] = *(const uint4*)&tbf[(size_t)(row0+rr)*512 + ks*64 + ch*8];
    }
    #pragma unroll
    for (int u=0;u<3;++u) {
      int i = tid + u*256; int rr = i>>3, ch = i&7;
      *(uint4*)&Bs[rr*72 + ch*8] = *(const uint4*)&Wtf[(size_t)rr*512 + ks*64 + ch*8];
    }
    __syncthreads();
    #pragma unroll
    for (int ksub=0; ksub<2; ++ksub) {
      bf16x8 av = *(bf16x8*)&As[(w*16+fr)*72 + ksub*32 + fg*8];
      #pragma unroll
      for (int n=0;n<6;++n) {
        bf16x8 bv = *(bf16x8*)&Bs[(n*16+fr)*72 + ksub*32 + fg*8];
        acc[n] = __builtin_amdgcn_mfma_f32_16x16x32_bf16(av, bv, acc[n], 0,0,0);
      }
    }
  }
  #pragma unroll
  for (int n=0;n<6;++n) {
    #pragma unroll
    for (int reg=0;reg<4;++reg) {
      int rloc = w*16 + fg*4 + reg;
      acc[n][reg] *= rp[rloc*4+0];
    }
  }
  // ---- seasonal phase: K=1024 ----
  for (int ks=0; ks<16; ++ks) {
    __syncthreads();
    #pragma unroll
    for (int u=0;u<2;++u) {
      int i = tid + u*256; int rr = i>>3, ch = i&7;
      *(uint4*)&As[rr*72 + ch*8] = *(const uint4*)&ybf[(size_t)(row0+rr)*1024 + ks*64 + ch*8];
    }
    #pragma unroll
    for (int u=0;u<3;++u) {
      int i = tid + u*256; int rr = i>>3, ch = i&7;
      *(uint4*)&Bs[rr*72 + ch*8] = *(const uint4*)&Wsf[(size_t)rr*1024 + ks*64 + ch*8];
    }
    __syncthreads();
    #pragma unroll
    for (int ksub=0; ksub<2; ++ksub) {
      bf16x8 av = *(bf16x8*)&As[(w*16+fr)*72 + ksub*32 + fg*8];
      #pragma unroll
      for (int n=0;n<6;++n) {
        bf16x8 bv = *(bf16x8*)&Bs[(n*16+fr)*72 + ksub*32 + fg*8];
        acc[n] = __builtin_amdgcn_mfma_f32_16x16x32_bf16(av, bv, acc[n], 0,0,0);
      }
    }
  }
  #pragma unroll
  for (int n=0;n<6;++n) {
    int col = n*16 + fr;
    float cs = csl[col], bc = bcl[col];
    #pragma unroll
    for (int reg=0;reg<4;++reg) {
      int rloc = w*16 + fg*4 + reg;
      float g = rp[rloc*4+1], meanv = rp[rloc*4+2], inva = rp[rloc*4+3];
      float val = acc[n][reg] + g*cs + bc;
      val = (val - rbl[rloc])*inva + meanv;
      out[(size_t)obase[rloc] + (size_t)col*C_] = val;
    }
  }
}

extern "C" void kernel_launch(void* const* d_in, const int* in_sizes, int n_in,
                              void* d_out, int out_size, void* d_ws, size_t ws_size,
                              hipStream_t stream) {
  const float* x      = (const float*)d_in[0];
  const float* rev_w  = (const float*)d_in[1];
  const float* rev_b  = (const float*)d_in[2];
  const float* fc1_w  = (const float*)d_in[3];
  const float* fc1_b  = (const float*)d_in[4];
  const float* bn1_w  = (const float*)d_in[5];
  const float* bn1_b  = (const float*)d_in[6];
  const float* conv_w = (const float*)d_in[7];
  const float* conv_b = (const float*)d_in[8];
  const float* bn2_w  = (const float*)d_in[9];
  const float* bn2_b  = (const float*)d_in[10];
  const float* fc2_w  = (const float*)d_in[11];
  const float* fc2_b  = (const float*)d_in[12];
  const float* m1_w   = (const float*)d_in[13];
  const float* m1_b   = (const float*)d_in[14];
  const float* m2_w   = (const float*)d_in[15];
  const float* m2_b   = (const float*)d_in[16];
  const float* gl     = (const float*)d_in[17];
  const float* ln_w   = (const float*)d_in[18];
  const float* ln_b   = (const float*)d_in[19];
  const float* seas_w = (const float*)d_in[20];
  const float* seas_b = (const float*)d_in[21];
  const float* tr_w   = (const float*)d_in[22];
  const float* tr_b   = (const float*)d_in[23];
  const float* fus_w  = (const float*)d_in[24];
  const float* fus_b  = (const float*)d_in[25];
  float* out = (float*)d_out;
  float* ws = (float*)d_ws;

  __hip_bfloat16* Wsf  = (__hip_bfloat16*)(ws);
  __hip_bfloat16* Wtf  = (__hip_bfloat16*)(ws + 49152);
  float* biasc   = ws + 73728;
  float* colsumT = ws + 73856;
  float* scale1  = ws + 73984;
  float* shift1  = ws + 74048;
  float* scale2  = ws + 74112;
  float* shift2  = ws + 74176;
  float* partials= ws + 74240;
  float* rowpar  = ws + 238592;
  float* s_raw   = ws + 320768;
  __hip_bfloat16* t_bf = (__hip_bfloat16*)(ws + 11168000);
  __hip_bfloat16* ybf  = (__hip_bfloat16*)(ws + 16427264);

  hipLaunchKernelGGL(k0_fold,  dim3(576),  dim3(256), 0, stream, seas_w, tr_w, fus_w, Wsf, Wtf);
  hipLaunchKernelGGL(k0b_bias, dim3(1),    dim3(128), 0, stream, seas_b, tr_b, fus_w, fus_b, tr_w, biasc, colsumT);
  hipLaunchKernelGGL(k1_revin_ema, dim3(BC_/64), dim3(256), 0, stream, x, rev_w, rev_b, s_raw, t_bf, rowpar);
  hipLaunchKernelGGL(k2_bn1stats, dim3(NBLK2_), dim3(256), 0, stream, s_raw, rowpar, fc1_w, fc1_b, partials);
  hipLaunchKernelGGL(k_bnreduce, dim3(64), dim3(256), 0, stream, partials, NBLK2_, bn1_w, bn1_b, scale1, shift1);
  hipLaunchKernelGGL(k3_bn2stats, dim3(NBLK2_), dim3(256), 0, stream, s_raw, rowpar, fc1_w, fc1_b, scale1, shift1, conv_w, conv_b, partials);
  hipLaunchKernelGGL(k_bnreduce, dim3(64), dim3(256), 0, stream, partials, NBLK2_, bn2_w, bn2_b, scale2, shift2);
  hipLaunchKernelGGL(k5a_pipeline, dim3(BC_/RB_), dim3(256), 0, stream,
    s_raw, rowpar, fc1_w, fc1_b, scale1, shift1, conv_w, conv_b,
    scale2, shift2, fc2_w, fc2_b, m1_w, m1_b, m2_w, m2_b, gl, ln_w, ln_b, ybf);
  hipLaunchKernelGGL(k5b_gemm, dim3(BC_/64), dim3(256), 0, stream,
    ybf, t_bf, Wsf, Wtf, rowpar, rev_b, biasc, colsumT, out);
}

// Round 6
// 553.559 us; speedup vs baseline: 4.5180x; 1.0839x over previous
//
#include <hip/hip_runtime.h>
#include <hip/hip_bf16.h>
#include <math.h>

#define B_    64
#define L_    512
#define C_    321
#define PRED_ 96
#define N_    64
#define HID_  32
#define BC_   (B_*C_)   // 20544
#define SROW_ 528       // padded stride for seasonal rows (520 used)
#define EPS_  1e-5f
#define ALPHA_ 0.2f
#define GR_   16        // rows per block in bn-stat kernels
#define RB_   8         // rows per block in k5a
#define NBLK2_ (BC_/GR_) // 1284
#define D64_  6.2771017353866808e-7f   // 0.8^64 (exact fp64 -> fp32)

typedef __attribute__((ext_vector_type(8))) short bf16x8;
typedef __attribute__((ext_vector_type(4))) float f32x4;

// Fast gelu: Abramowitz-Stegun 7.1.26 erf approximation, |eps|<=1.5e-7.
// gelu(x) = 0.5x + 0.5|x|*erf(|x|/sqrt2); branch-free, 2 hw transcendentals.
__device__ __forceinline__ float gelu_f(float x){
  float ax = fabsf(x);
  float z  = ax * 0.70710678118654752440f;
  float t  = __builtin_amdgcn_rcpf(fmaf(0.3275911f, z, 1.0f));
  float poly = fmaf(fmaf(fmaf(fmaf(1.061405429f, t, -1.453152027f),
                   t, 1.421413741f), t, -0.284496736f), t, 0.254829592f) * t;
  float e  = __expf(-z*z);
  float erfp = fmaf(-poly, e, 1.0f);
  return fmaf(0.5f*ax, erfp, 0.5f*x);
}
__device__ __forceinline__ unsigned short bf16bits(float x){
  __hip_bfloat16 h = __float2bfloat16(x);
  return *(unsigned short*)&h;
}

// ---------- K0: fold seas/tr matmuls through fus; store bf16 col-major [j][k] ----------
__global__ __launch_bounds__(256) void k0_fold(
    const float* __restrict__ seas_w, const float* __restrict__ tr_w,
    const float* __restrict__ fus_w,
    __hip_bfloat16* __restrict__ Wsf, __hip_bfloat16* __restrict__ Wtf) {
  int idx = blockIdx.x*256 + threadIdx.x;
  if (idx >= 96*1536) return;
  int j = idx / 1536, k = idx - j*1536;
  float acc = 0.f;
  if (k < 1024) {
    for (int i=0;i<96;++i) acc = fmaf(fus_w[j*192+i], seas_w[i*1024+k], acc);
    Wsf[(size_t)j*1024 + k] = __float2bfloat16(acc);
  } else {
    int l = k - 1024;
    for (int i=0;i<96;++i) acc = fmaf(fus_w[j*192+96+i], tr_w[i*512+l], acc);
    Wtf[(size_t)j*512 + l] = __float2bfloat16(acc);
  }
}

// ---------- K0b: combined bias + column-sum of folded trend matrix ----------
__global__ void k0b_bias(
    const float* __restrict__ seas_b, const float* __restrict__ tr_b,
    const float* __restrict__ fus_w, const float* __restrict__ fus_b,
    const float* __restrict__ tr_w,
    float* __restrict__ biasc, float* __restrict__ colsumT) {
  __shared__ float rowsum[96];
  int t = threadIdx.x;
  if (t < 96) {
    float s = 0.f;
    for (int l=0;l<512;++l) s += tr_w[t*512+l];
    rowsum[t] = s;
  }
  __syncthreads();
  if (t < 96) {
    float acc = fus_b[t], cs = 0.f;
    for (int i=0;i<96;++i) {
      acc = fmaf(fus_w[t*192+i],    seas_b[i], acc);
      acc = fmaf(fus_w[t*192+96+i], tr_b[i],   acc);
      cs  = fmaf(fus_w[t*192+96+i], rowsum[i], cs);
    }
    biasc[t] = acc; colsumT[t] = cs;
  }
}

// ---------- K1: RevIN stats + chunked EMA scan (8 chunks x 32 rows / block) ----------
// Inter-chunk carry via the EXACT linear recurrence t_end(j)=loc_j+0.8^64*t_end(j-1),
// so the split introduces no approximation at all.
__global__ __launch_bounds__(256) void k1_revin_ema(
    const float* __restrict__ x, const float* __restrict__ rev_w, const float* __restrict__ rev_b,
    float* __restrict__ s_raw, __hip_bfloat16* __restrict__ t_bf, float* __restrict__ rowpar) {
  __shared__ float lf[8][32];
  __shared__ float psum[8][32], psq[8][32];
  int tid = threadIdx.x;
  int q = tid >> 5, r = tid & 31;
  int row = blockIdx.x*32 + r;
  int b = row / C_, c = row - b*C_;
  const float* xp = x + (size_t)b*L_*C_ + c;
  int l0 = q*64;
  float tloc = 0.f, sum = 0.f, sq = 0.f;
  for (int i=0;i<64;++i) {
    float v = xp[(size_t)(l0+i)*C_];
    sum += v; sq = fmaf(v,v,sq);
    tloc = (q==0 && i==0) ? v : fmaf(ALPHA_, v, 0.8f*tloc);
  }
  lf[q][r] = tloc; psum[q][r] = sum; psq[q][r] = sq;
  __syncthreads();
  // exact carry-in for this chunk
  float cin = 0.f;
  for (int j=0;j<q;++j) cin = fmaf(D64_, cin, lf[j][r]);
  if (q==0) {
    float S=0.f, Q=0.f;
    for (int qq=0;qq<8;++qq){ S += psum[qq][r]; Q += psq[qq][r]; }
    float mean = S*(1.0f/512.0f);
    float var  = (Q - S*S*(1.0f/512.0f))*(1.0f/511.0f);
    var = fmaxf(var, 0.f);
    float stdv = sqrtf(var) + EPS_;
    float rwc = rev_w[c], rbc = rev_b[c];
    float a = rwc / stdv;
    float g = rbc - mean*a;
    float inva = stdv / rwc;
    ((float4*)rowpar)[row] = make_float4(a, g, mean, inva);
  }
  float loc = 0.f, f = 1.f, vlast = 0.f, tlast = 0.f;
  for (int i=0;i<64;++i) {
    float v = xp[(size_t)(l0+i)*C_];
    loc = (q==0 && i==0) ? v : fmaf(ALPHA_, v, 0.8f*loc);
    f *= 0.8f;
    float tt = fmaf(f, cin, loc);
    s_raw[(size_t)row*SROW_ + l0 + i] = v - tt;
    t_bf[(size_t)row*512 + l0 + i] = __float2bfloat16(tt);
    vlast = v; tlast = tt;
  }
  if (q==7) {
    float slast = vlast - tlast;
    for (int k=0;k<8;++k) s_raw[(size_t)row*SROW_ + 512 + k] = slast;
  }
}

// ---------- K2: BN1 statistics of gelu(fc1(sp)) — weights via scalar path ----------
__global__ __launch_bounds__(256) void k2_bn1stats(
    const float* __restrict__ s_raw, const float* __restrict__ rowpar,
    const float* __restrict__ fc1_w, const float* __restrict__ fc1_b,
    float* __restrict__ partials) {
  __shared__ float sl[GR_*SROW_];
  __shared__ float al[GR_];
  __shared__ float red[2][GR_*64];
  int t = threadIdx.x;
  int row0 = blockIdx.x*GR_;
  if (t < GR_) al[t] = rowpar[(size_t)(row0+t)*4];
  __syncthreads();
  for (int idx=t; idx<GR_*520; idx+=256) {
    int rr = idx/520, cc = idx - rr*520;
    sl[rr*SROW_+cc] = s_raw[(size_t)(row0+rr)*SROW_+cc] * al[rr];
  }
  __syncthreads();
  int lr = t >> 4, ng = t & 15;
  for (int q=0;q<4;++q) {
    int n = ng + 16*q;
    float sp[16];
    #pragma unroll
    for (int p=0;p<16;++p) sp[p] = sl[lr*SROW_ + n*8 + p];
    float s1=0.f, s2=0.f;
    #pragma unroll
    for (int hid=0; hid<32; ++hid) {
      float acc = fc1_b[hid];
      #pragma unroll
      for (int p=0;p<16;++p) acc = fmaf(sp[p], fc1_w[hid*16+p], acc);
      float gv = gelu_f(acc);
      s1 += gv; s2 = fmaf(gv,gv,s2);
    }
    red[0][lr*64+n] = s1;
    red[1][lr*64+n] = s2;
  }
  __syncthreads();
  if (t < 64) {
    float S1=0.f, S2=0.f;
    for (int lr2=0; lr2<GR_; ++lr2) { S1 += red[0][lr2*64+t]; S2 += red[1][lr2*64+t]; }
    partials[((size_t)blockIdx.x*64+t)*2+0] = S1;
    partials[((size_t)blockIdx.x*64+t)*2+1] = S2;
  }
}

// ---------- bn reduce ----------
__global__ __launch_bounds__(256) void k_bnreduce(
    const float* __restrict__ partials, int nblk,
    const float* __restrict__ bnw, const float* __restrict__ bnb,
    float* __restrict__ scale, float* __restrict__ shift) {
  __shared__ float red[2][256];
  int n = blockIdx.x, t = threadIdx.x;
  float s1=0.f, s2=0.f;
  for (int i=t; i<nblk; i+=256) {
    s1 += partials[((size_t)i*64+n)*2+0];
    s2 += partials[((size_t)i*64+n)*2+1];
  }
  red[0][t]=s1; red[1][t]=s2;
  __syncthreads();
  for (int off=128; off>0; off>>=1) {
    if (t<off) { red[0][t]+=red[0][t+off]; red[1][t]+=red[1][t+off]; }
    __syncthreads();
  }
  if (t==0) {
    const float count = (float)BC_ * 32.0f;
    float mu = red[0][0]/count;
    float var = red[1][0]/count - mu*mu;
    float sc = rsqrtf(var + EPS_) * bnw[n];
    scale[n] = sc;
    shift[n] = bnb[n] - mu*sc;
  }
}

// ---------- K3: BN2 statistics (in-place conv; weights via scalar path) ----------
__global__ __launch_bounds__(256) void k3_bn2stats(
    const float* __restrict__ s_raw, const float* __restrict__ rowpar,
    const float* __restrict__ fc1_w, const float* __restrict__ fc1_b,
    const float* __restrict__ scale1, const float* __restrict__ shift1,
    const float* __restrict__ conv_w, const float* __restrict__ conv_b,
    float* __restrict__ partials) {
  __shared__ float sl[GR_*SROW_];
  __shared__ float al[GR_];
  __shared__ float sc1[64], sh1[64], cw[192], cb[64];
  __shared__ float red[2][GR_*64];
  int t = threadIdx.x;
  int row0 = blockIdx.x*GR_;
  if (t < GR_) al[t] = rowpar[(size_t)(row0+t)*4];
  if (t < 64) { sc1[t]=scale1[t]; sh1[t]=shift1[t]; cb[t]=conv_b[t]; }
  if (t >= 64 && t < 256) cw[t-64] = conv_w[t-64];
  __syncthreads();
  for (int idx=t; idx<GR_*520; idx+=256) {
    int rr = idx/520, cc = idx - rr*520;
    sl[rr*SROW_+cc] = s_raw[(size_t)(row0+rr)*SROW_+cc] * al[rr];
  }
  __syncthreads();
  int lr = t >> 4, ng = t & 15;
  for (int q=0;q<4;++q) {
    int n = ng + 16*q;
    float sp[16];
    #pragma unroll
    for (int p=0;p<16;++p) sp[p] = sl[lr*SROW_ + n*8 + p];
    float scn = sc1[n], shn = sh1[n];
    float h[32];
    #pragma unroll
    for (int hid=0; hid<32; ++hid) {
      float acc = fc1_b[hid];
      #pragma unroll
      for (int p=0;p<16;++p) acc = fmaf(sp[p], fc1_w[hid*16+p], acc);
      h[hid] = fmaf(gelu_f(acc), scn, shn);
    }
    float w0=cw[n*3], wm=cw[n*3+1], wpp=cw[n*3+2], cbn=cb[n];
    float s1=0.f, s2=0.f, prev=0.f;
    #pragma unroll
    for (int k2=0;k2<32;++k2) {
      float cur = h[k2];
      float cv = cbn;
      cv = fmaf(prev, w0, cv);
      cv = fmaf(cur, wm, cv);
      if (k2<31) cv = fmaf(h[k2+1], wpp, cv);
      float gv = gelu_f(cv);
      s1 += gv; s2 = fmaf(gv,gv,s2);
      prev = cur;
    }
    red[0][lr*64+n]=s1; red[1][lr*64+n]=s2;
  }
  __syncthreads();
  if (t < 64) {
    float S1=0.f, S2=0.f;
    for (int lr2=0; lr2<GR_; ++lr2) { S1 += red[0][lr2*64+t]; S2 += red[1][lr2*64+t]; }
    partials[((size_t)blockIdx.x*64+t)*2+0] = S1;
    partials[((size_t)blockIdx.x*64+t)*2+1] = S2;
  }
}

// ---------- K5a: per-row pipeline -> LayerNorm'd y (bf16) ----------
__global__ __launch_bounds__(256) void k5a_pipeline(
    const float* __restrict__ s_raw, const float* __restrict__ rowpar,
    const float* __restrict__ fc1_w, const float* __restrict__ fc1_b,
    const float* __restrict__ scale1, const float* __restrict__ shift1,
    const float* __restrict__ conv_w, const float* __restrict__ conv_b,
    const float* __restrict__ scale2, const float* __restrict__ shift2,
    const float* __restrict__ fc2_w, const float* __restrict__ fc2_b,
    const float* __restrict__ m1_w, const float* __restrict__ m1_b,
    const float* __restrict__ m2_w, const float* __restrict__ m2_b,
    const float* __restrict__ gl_scale,
    const float* __restrict__ ln_w, const float* __restrict__ ln_b,
    __hip_bfloat16* __restrict__ ybf) {
  __shared__ float sl[RB_*SROW_];
  __shared__ float pl[RB_*64];
  __shared__ float hl[RB_*128];
  __shared__ float wl[RB_*64];
  __shared__ float rp[RB_];
  __shared__ float cw[192], cb[64];
  __shared__ float sc1[64], sh1[64], sc2[64], sh2[64];
  int t = threadIdx.x;
  int row0 = blockIdx.x*RB_;
  if (t < RB_) rp[t] = rowpar[(size_t)(row0+t)*4];
  if (t<64) { sc1[t]=scale1[t]; sh1[t]=shift1[t]; sc2[t]=scale2[t]; sh2[t]=shift2[t]; cb[t]=conv_b[t]; }
  if (t>=64 && t<256) cw[t-64]=conv_w[t-64];
  __syncthreads();
  for (int idx=t; idx<RB_*520; idx+=256) {
    int rr = idx/520, cc = idx - rr*520;
    sl[rr*SROW_+cc] = s_raw[(size_t)(row0+rr)*SROW_+cc] * rp[rr];
  }
  __syncthreads();
  float glv = gl_scale[0];
  // P1: pooled
  for (int idx=t; idx<RB_*64; idx+=256) {
    int rr = idx>>6, n = idx&63;
    float s=0.f;
    #pragma unroll
    for (int p=0;p<16;++p) s += sl[rr*SROW_ + n*8 + p];
    pl[idx] = s*(1.0f/16.0f);
  }
  __syncthreads();
  // P2: hidden = gelu(m1 @ pooled + b)
  for (int idx=t; idx<RB_*128; idx+=256) {
    int rr = idx>>7, i = idx&127;
    float acc = m1_b[i];
    for (int k2=0;k2<64;++k2) acc = fmaf(pl[rr*64+k2], m1_w[i*64+k2], acc);
    hl[idx] = gelu_f(acc);
  }
  __syncthreads();
  // P3: w = sigmoid(m2 @ hidden + b)
  for (int idx=t; idx<RB_*64; idx+=256) {
    int rr = idx>>6, n = idx&63;
    float acc = m2_b[n];
    for (int k2=0;k2<128;++k2) acc = fmaf(hl[rr*128+k2], m2_w[n*128+k2], acc);
    wl[idx] = 1.0f/(1.0f + __expf(-acc));
  }
  __syncthreads();
  // P4: per-(row,n) pipeline
  for (int idx=t; idx<RB_*64; idx+=256) {
    int rr = idx>>6, n = idx&63;
    // stage 1: fc1 + gelu + bn1
    float h[32];
    {
      float sp[16];
      #pragma unroll
      for (int p=0;p<16;++p) sp[p] = sl[rr*SROW_ + n*8 + p];
      float scn=sc1[n], shn=sh1[n];
      #pragma unroll
      for (int hid=0;hid<32;++hid) {
        float acc=fc1_b[hid];
        #pragma unroll
        for (int p=0;p<16;++p) acc=fmaf(sp[p], fc1_w[hid*16+p], acc);
        h[hid]=fmaf(gelu_f(acc), scn, shn);
      }
    }
    // stage 2: in-place conv + gelu + bn2
    {
      float w0=cw[n*3], wm=cw[n*3+1], wpp=cw[n*3+2], cbn=cb[n];
      float sc2n=sc2[n], sh2n=sh2[n];
      float prev=0.f;
      #pragma unroll
      for (int k2=0;k2<32;++k2) {
        float cur = h[k2];
        float cv = cbn;
        cv = fmaf(prev, w0, cv);
        cv = fmaf(cur, wm, cv);
        if (k2<31) cv = fmaf(h[k2+1], wpp, cv);
        h[k2] = fmaf(gelu_f(cv), sc2n, sh2n);
        prev = cur;
      }
    }
    // stage 3: fc2 accumulate
    float yv[16];
    #pragma unroll
    for (int p=0;p<16;++p) {
      float acc=fc2_b[p];
      #pragma unroll
      for (int hid=0;hid<32;++hid) acc=fmaf(h[hid], fc2_w[p*32+hid], acc);
      yv[p]=acc;
    }
    // stage 4: residual (sp from LDS) + LN + packed bf16 store
    float smul = 3.0f + glv*wl[idx];
    float mu=0.f;
    #pragma unroll
    for (int p=0;p<16;++p) {
      yv[p]=fmaf(sl[rr*SROW_ + n*8 + p], smul, yv[p]);
      mu+=yv[p];
    }
    mu *= (1.0f/16.0f);
    float var=0.f;
    #pragma unroll
    for (int p=0;p<16;++p){ float d=yv[p]-mu; var=fmaf(d,d,var); }
    var *= (1.0f/16.0f);
    float rs = rsqrtf(var + EPS_);
    unsigned int wds[8];
    #pragma unroll
    for (int j=0;j<8;++j) {
      unsigned int lo = bf16bits(fmaf((yv[2*j]-mu)*rs,   ln_w[2*j],   ln_b[2*j]));
      unsigned int hi = bf16bits(fmaf((yv[2*j+1]-mu)*rs, ln_w[2*j+1], ln_b[2*j+1]));
      wds[j] = lo | (hi<<16);
    }
    size_t ybase = (size_t)(row0+rr)*1024 + n*16;
    uint4* dst = (uint4*)&ybf[ybase];
    dst[0] = make_uint4(wds[0],wds[1],wds[2],wds[3]);
    dst[1] = make_uint4(wds[4],wds[5],wds[6],wds[7]);
  }
}

// ---------- K5b: bf16 MFMA GEMM  out = y@Wsf^T + a*(t@Wtf^T) + g*colsum + biasc ----------
__global__ __launch_bounds__(256) void k5b_gemm(
    const __hip_bfloat16* __restrict__ ybf, const __hip_bfloat16* __restrict__ tbf,
    const __hip_bfloat16* __restrict__ Wsf, const __hip_bfloat16* __restrict__ Wtf,
    const float* __restrict__ rowpar, const float* __restrict__ rev_b,
    const float* __restrict__ biasc, const float* __restrict__ colsumT,
    float* __restrict__ out) {
  __shared__ __align__(16) __hip_bfloat16 As[64*72];
  __shared__ __align__(16) __hip_bfloat16 Bs[96*72];
  __shared__ float rp[256];
  __shared__ float rbl[64];
  __shared__ int   obase[64];
  __shared__ float bcl[96], csl[96];
  int tid = threadIdx.x;
  int row0 = blockIdx.x*64;
  rp[tid] = rowpar[(size_t)row0*4 + tid];
  if (tid < 64) {
    int row = row0 + tid; int b = row/C_; int c = row - b*C_;
    rbl[tid] = rev_b[c]; obase[tid] = b*PRED_*C_ + c;
  }
  if (tid >= 128 && tid < 224) { bcl[tid-128]=biasc[tid-128]; csl[tid-128]=colsumT[tid-128]; }
  int lane = tid & 63, w = tid >> 6;
  int fr = lane & 15, fg = lane >> 4;
  f32x4 acc[6];
  #pragma unroll
  for (int n=0;n<6;++n) acc[n] = (f32x4){0.f,0.f,0.f,0.f};
  // ---- trend phase: K=512 ----
  for (int ks=0; ks<8; ++ks) {
    __syncthreads();
    #pragma unroll
    for (int u=0;u<2;++u) {
      int i = tid + u*256; int rr = i>>3, ch = i&7;
      *(uint4*)&As[rr*72 + ch*8] = *(const uint4*)&tbf[(size_t)(row0+rr)*512 + ks*64 + ch*8];
    }
    #pragma unroll
    for (int u=0;u<3;++u) {
      int i = tid + u*256; int rr = i>>3, ch = i&7;
      *(uint4*)&Bs[rr*72 + ch*8] = *(const uint4*)&Wtf[(size_t)rr*512 + ks*64 + ch*8];
    }
    __syncthreads();
    #pragma unroll
    for (int ksub=0; ksub<2; ++ksub) {
      bf16x8 av = *(bf16x8*)&As[(w*16+fr)*72 + ksub*32 + fg*8];
      #pragma unroll
      for (int n=0;n<6;++n) {
        bf16x8 bv = *(bf16x8*)&Bs[(n*16+fr)*72 + ksub*32 + fg*8];
        acc[n] = __builtin_amdgcn_mfma_f32_16x16x32_bf16(av, bv, acc[n], 0,0,0);
      }
    }
  }
  #pragma unroll
  for (int n=0;n<6;++n) {
    #pragma unroll
    for (int reg=0;reg<4;++reg) {
      int rloc = w*16 + fg*4 + reg;
      acc[n][reg] *= rp[rloc*4+0];
    }
  }
  // ---- seasonal phase: K=1024 ----
  for (int ks=0; ks<16; ++ks) {
    __syncthreads();
    #pragma unroll
    for (int u=0;u<2;++u) {
      int i = tid + u*256; int rr = i>>3, ch = i&7;
      *(uint4*)&As[rr*72 + ch*8] = *(const uint4*)&ybf[(size_t)(row0+rr)*1024 + ks*64 + ch*8];
    }
    #pragma unroll
    for (int u=0;u<3;++u) {
      int i = tid + u*256; int rr = i>>3, ch = i&7;
      *(uint4*)&Bs[rr*72 + ch*8] = *(const uint4*)&Wsf[(size_t)rr*1024 + ks*64 + ch*8];
    }
    __syncthreads();
    #pragma unroll
    for (int ksub=0; ksub<2; ++ksub) {
      bf16x8 av = *(bf16x8*)&As[(w*16+fr)*72 + ksub*32 + fg*8];
      #pragma unroll
      for (int n=0;n<6;++n) {
        bf16x8 bv = *(bf16x8*)&Bs[(n*16+fr)*72 + ksub*32 + fg*8];
        acc[n] = __builtin_amdgcn_mfma_f32_16x16x32_bf16(av, bv, acc[n], 0,0,0);
      }
    }
  }
  #pragma unroll
  for (int n=0;n<6;++n) {
    int col = n*16 + fr;
    float cs = csl[col], bc = bcl[col];
    #pragma unroll
    for (int reg=0;reg<4;++reg) {
      int rloc = w*16 + fg*4 + reg;
      float g = rp[rloc*4+1], meanv = rp[rloc*4+2], inva = rp[rloc*4+3];
      float val = acc[n][reg] + g*cs + bc;
      val = (val - rbl[rloc])*inva + meanv;
      out[(size_t)obase[rloc] + (size_t)col*C_] = val;
    }
  }
}

extern "C" void kernel_launch(void* const* d_in, const int* in_sizes, int n_in,
                              void* d_out, int out_size, void* d_ws, size_t ws_size,
                              hipStream_t stream) {
  const float* x      = (const float*)d_in[0];
  const float* rev_w  = (const float*)d_in[1];
  const float* rev_b  = (const float*)d_in[2];
  const float* fc1_w  = (const float*)d_in[3];
  const float* fc1_b  = (const float*)d_in[4];
  const float* bn1_w  = (const float*)d_in[5];
  const float* bn1_b  = (const float*)d_in[6];
  const float* conv_w = (const float*)d_in[7];
  const float* conv_b = (const float*)d_in[8];
  const float* bn2_w  = (const float*)d_in[9];
  const float* bn2_b  = (const float*)d_in[10];
  const float* fc2_w  = (const float*)d_in[11];
  const float* fc2_b  = (const float*)d_in[12];
  const float* m1_w   = (const float*)d_in[13];
  const float* m1_b   = (const float*)d_in[14];
  const float* m2_w   = (const float*)d_in[15];
  const float* m2_b   = (const float*)d_in[16];
  const float* gl     = (const float*)d_in[17];
  const float* ln_w   = (const float*)d_in[18];
  const float* ln_b   = (const float*)d_in[19];
  const float* seas_w = (const float*)d_in[20];
  const float* seas_b = (const float*)d_in[21];
  const float* tr_w   = (const float*)d_in[22];
  const float* tr_b   = (const float*)d_in[23];
  const float* fus_w  = (const float*)d_in[24];
  const float* fus_b  = (const float*)d_in[25];
  float* out = (float*)d_out;
  float* ws = (float*)d_ws;

  __hip_bfloat16* Wsf  = (__hip_bfloat16*)(ws);
  __hip_bfloat16* Wtf  = (__hip_bfloat16*)(ws + 49152);
  float* biasc   = ws + 73728;
  float* colsumT = ws + 73856;
  float* scale1  = ws + 73984;
  float* shift1  = ws + 74048;
  float* scale2  = ws + 74112;
  float* shift2  = ws + 74176;
  float* partials= ws + 74240;
  float* rowpar  = ws + 238592;
  float* s_raw   = ws + 320768;
  __hip_bfloat16* t_bf = (__hip_bfloat16*)(ws + 11168000);
  __hip_bfloat16* ybf  = (__hip_bfloat16*)(ws + 16427264);

  hipLaunchKernelGGL(k0_fold,  dim3(576),  dim3(256), 0, stream, seas_w, tr_w, fus_w, Wsf, Wtf);
  hipLaunchKernelGGL(k0b_bias, dim3(1),    dim3(128), 0, stream, seas_b, tr_b, fus_w, fus_b, tr_w, biasc, colsumT);
  hipLaunchKernelGGL(k1_revin_ema, dim3(BC_/32), dim3(256), 0, stream, x, rev_w, rev_b, s_raw, t_bf, rowpar);
  hipLaunchKernelGGL(k2_bn1stats, dim3(NBLK2_), dim3(256), 0, stream, s_raw, rowpar, fc1_w, fc1_b, partials);
  hipLaunchKernelGGL(k_bnreduce, dim3(64), dim3(256), 0, stream, partials, NBLK2_, bn1_w, bn1_b, scale1, shift1);
  hipLaunchKernelGGL(k3_bn2stats, dim3(NBLK2_), dim3(256), 0, stream, s_raw, rowpar, fc1_w, fc1_b, scale1, shift1, conv_w, conv_b, partials);
  hipLaunchKernelGGL(k_bnreduce, dim3(64), dim3(256), 0, stream, partials, NBLK2_, bn2_w, bn2_b, scale2, shift2);
  hipLaunchKernelGGL(k5a_pipeline, dim3(BC_/RB_), dim3(256), 0, stream,
    s_raw, rowpar, fc1_w, fc1_b, scale1, shift1, conv_w, conv_b,
    scale2, shift2, fc2_w, fc2_b, m1_w, m1_b, m2_w, m2_b, gl, ln_w, ln_b, ybf);
  hipLaunchKernelGGL(k5b_gemm, dim3(BC_/64), dim3(256), 0, stream,
    ybf, t_bf, Wsf, Wtf, rowpar, rev_b, biasc, colsumT, out);
}